// Round 6
// baseline (1983.329 us; speedup 1.0000x reference)
//
#include <hip/hip_runtime.h>
#include <math.h>

typedef unsigned short u16;
typedef unsigned int u32;
typedef __bf16 bf16x8 __attribute__((ext_vector_type(8)));
typedef float f32x4 __attribute__((ext_vector_type(4)));

// ---------- helpers ----------
__device__ __forceinline__ u16 f2bf(float f){
  unsigned u = __float_as_uint(f);
  unsigned r = u + 0x7fffu + ((u >> 16) & 1u);
  return (u16)(r >> 16);
}
__device__ __forceinline__ float bf2f(u16 h){ return __uint_as_float(((unsigned)h) << 16); }

__device__ __forceinline__ void gload_lds16(const void* g, void* l){
  __builtin_amdgcn_global_load_lds(
      (__attribute__((address_space(1))) void*)(g),
      (__attribute__((address_space(3))) void*)(l), 16, 0, 0);
}
__device__ __forceinline__ f32x4 mfma16(bf16x8 a, bf16x8 b, f32x4 c){
  return __builtin_amdgcn_mfma_f32_16x16x32_bf16(a, b, c, 0, 0, 0);
}
__device__ __forceinline__ float gelu_f(float x){
  float a = 0.7978845608028654f * (x + 0.044715f * x * x * x);
  a = fminf(fmaxf(a, -15.f), 15.f);
  float t = __expf(2.f * a);
  return 0.5f * x * (1.f + (t - 1.f) / (t + 1.f));
}

// ---------- transpose + f32->bf16 convert: W[l][K][N] -> Wt[l][N][K] ----------
__global__ __launch_bounds__(256) void transcvt_l(const float* __restrict__ W,
                                                  u16* __restrict__ Wt, int K, int N){
  int l = blockIdx.z;
  W  += (size_t)l * K * N;
  Wt += (size_t)l * N * K;
  __shared__ float tile[32][33];
  int tx = threadIdx.x & 31, ty = threadIdx.x >> 5;
  int n0 = blockIdx.x * 32, k0 = blockIdx.y * 32;
  #pragma unroll
  for (int j = 0; j < 32; j += 8)
    tile[ty + j][tx] = W[(size_t)(k0 + ty + j) * N + n0 + tx];
  __syncthreads();
  #pragma unroll
  for (int j = 0; j < 32; j += 8)
    Wt[(size_t)(n0 + ty + j) * K + k0 + tx] = f2bf(tile[tx][ty + j]);
}

// ---------- embedding + layernorm -> bf16 x ----------
__global__ __launch_bounds__(256) void embed_ln(const int* __restrict__ ids,
    const int* __restrict__ tts, const float* __restrict__ we, const float* __restrict__ pe,
    const float* __restrict__ te, const float* __restrict__ g, const float* __restrict__ bb,
    u16* __restrict__ xb){
  int tok = blockIdx.x * 4 + (threadIdx.x >> 6);
  int lane = threadIdx.x & 63;
  int s = tok & 511;
  int id = ids[tok], tt = tts[tok];
  float e[12]; float sum = 0.f, sq = 0.f;
  #pragma unroll
  for (int j = 0; j < 12; ++j){
    int c = lane + j * 64;
    float v = we[(size_t)id * 768 + c] + pe[(size_t)s * 768 + c] + te[(size_t)tt * 768 + c];
    e[j] = v; sum += v; sq += v * v;
  }
  #pragma unroll
  for (int o = 1; o < 64; o <<= 1){ sum += __shfl_xor(sum, o); sq += __shfl_xor(sq, o); }
  float mean = sum * (1.f / 768.f);
  float var = sq * (1.f / 768.f) - mean * mean;
  float inv = rsqrtf(var + 1e-12f);
  size_t base = (size_t)tok * 768;
  #pragma unroll
  for (int j = 0; j < 12; ++j){
    int c = lane + j * 64;
    xb[base + c] = f2bf((e[j] - mean) * inv * g[c] + bb[c]);
  }
}

// ---------- partial-sum + bias + residual + layernorm ----------
template<int P>
__global__ __launch_bounds__(256) void res_ln_p(const u16* __restrict__ parts,
    const u16* __restrict__ res, const float* __restrict__ bias,
    const float* __restrict__ g, const float* __restrict__ bb, u16* __restrict__ xout){
  int tok = blockIdx.x * 4 + (threadIdx.x >> 6);
  int lane = threadIdx.x & 63;
  size_t base = (size_t)tok * 768;
  const size_t MN = 4096ULL * 768;
  float v[12]; float sum = 0.f, sq = 0.f;
  #pragma unroll
  for (int j = 0; j < 3; ++j){
    int c = j * 256 + lane * 4;
    ushort4 r = *(const ushort4*)(res + base + c);
    f32x4 bsv = *(const f32x4*)(bias + c);
    const u16* rp = (const u16*)&r;
    float f[4];
    #pragma unroll
    for (int e = 0; e < 4; ++e) f[e] = bf2f(rp[e]) + bsv[e];
    #pragma unroll
    for (int p = 0; p < P; ++p){
      ushort4 a = *(const ushort4*)(parts + p * MN + base + c);
      const u16* ap = (const u16*)&a;
      #pragma unroll
      for (int e = 0; e < 4; ++e) f[e] += bf2f(ap[e]);
    }
    #pragma unroll
    for (int e = 0; e < 4; ++e){
      v[j * 4 + e] = f[e]; sum += f[e]; sq += f[e] * f[e];
    }
  }
  #pragma unroll
  for (int o = 1; o < 64; o <<= 1){ sum += __shfl_xor(sum, o); sq += __shfl_xor(sq, o); }
  float mean = sum * (1.f / 768.f);
  float var = sq * (1.f / 768.f) - mean * mean;
  float inv = rsqrtf(var + 1e-12f);
  #pragma unroll
  for (int j = 0; j < 3; ++j){
    int c = j * 256 + lane * 4;
    f32x4 gs = *(const f32x4*)(g + c);
    f32x4 bs = *(const f32x4*)(bb + c);
    ushort4 o; u16* op = (u16*)&o;
    #pragma unroll
    for (int e = 0; e < 4; ++e)
      op[e] = f2bf((v[j * 4 + e] - mean) * inv * gs[e] + bs[e]);
    *(ushort4*)(xout + base + c) = o;
  }
}

// ---------- GEMM: C = A[M][K](bf16) * Bt[N][K]^T (bf16) + bias ----------
// BK=64, double-buffered LDS, 1 barrier per K-step (prefetch issued before MFMA,
// drained by the end-of-iteration __syncthreads vmcnt(0)).
// EPI 1: gelu -> bf16 ; EPI 3: QKV (Q,K -> Cout; V -> Cout2 transposed [bh][d][s])
template<int EPI, int XSPLIT>
__global__ __launch_bounds__(256, 2)
void gemm_bt(const u16* __restrict__ A, const u16* __restrict__ Bt,
             const float* __restrict__ bias, void* __restrict__ Cout,
             void* __restrict__ Cout2, int M, int N, int K){
  __shared__ u16 lA[2][128 * 64];
  __shared__ u16 lB[2][128 * 64];
  const int tid = threadIdx.x, lane = tid & 63, wv = tid >> 6;
  const int wm = wv >> 1, wn = wv & 1;
  const int gx = gridDim.x, gy = gridDim.y;
  int bid = blockIdx.y * gx + blockIdx.x;
  int xcd = bid & 7, idx = bid >> 3;
  int bx, by;
  if (XSPLIT == 2){
    int cw = gx >> 1, ch = gy >> 2;
    bx = (xcd >> 2) * cw + idx % cw;
    by = (xcd & 3) * ch + idx / cw;
  } else {
    int ch = gy >> 3;
    bx = idx % gx;
    by = xcd * ch + idx / gx;
  }
  const int row0 = by * 128, col0 = bx * 128;
  auto STAGE = [&](int buf, int k0){
    #pragma unroll
    for (int s = 0; s < 4; ++s){
      int i = s * 256 + tid;
      int r = i >> 3, p = i & 7;
      int sk = k0 + ((p ^ (r & 7)) << 3);
      gload_lds16(A + (size_t)(row0 + r) * K + sk, (char*)lA[buf] + i * 16);
      gload_lds16(Bt + (size_t)(col0 + r) * K + sk, (char*)lB[buf] + i * 16);
    }
  };
  f32x4 acc[4][4] = {};
  const int nt = K >> 6;
  STAGE(0, 0);
  __syncthreads();
  int cur = 0;
  for (int t = 0; t < nt; ++t){
    if (t + 1 < nt) STAGE(cur ^ 1, (t + 1) << 6);
    int g = lane >> 4;
    __builtin_amdgcn_s_setprio(1);
    #pragma unroll
    for (int kk = 0; kk < 2; ++kk){
      bf16x8 af[4], bfv[4];
      #pragma unroll
      for (int m = 0; m < 4; ++m){
        int r = wm * 64 + m * 16 + (lane & 15);
        af[m] = *(const bf16x8*)((const char*)lA[cur] + r * 128 + (((kk * 4 + g) ^ (r & 7)) << 4));
      }
      #pragma unroll
      for (int n = 0; n < 4; ++n){
        int r = wn * 64 + n * 16 + (lane & 15);
        bfv[n] = *(const bf16x8*)((const char*)lB[cur] + r * 128 + (((kk * 4 + g) ^ (r & 7)) << 4));
      }
      #pragma unroll
      for (int m = 0; m < 4; ++m)
        #pragma unroll
        for (int n = 0; n < 4; ++n)
          acc[m][n] = mfma16(af[m], bfv[n], acc[m][n]);
    }
    __builtin_amdgcn_s_setprio(0);
    __syncthreads();
    cur ^= 1;
  }
  if (EPI == 3 && col0 >= 1536){
    u16* Vt = (u16*)Cout2;
    #pragma unroll
    for (int n = 0; n < 4; ++n){
      int gc = col0 + wn * 64 + n * 16 + (lane & 15);
      float bv = bias[gc];
      int vcol = gc - 1536, hh = vcol >> 6, dd = vcol & 63;
      #pragma unroll
      for (int m = 0; m < 4; ++m){
        int gr = row0 + wm * 64 + m * 16 + (lane >> 4) * 4;
        int bbi = gr >> 9, ss = gr & 511;
        u32 w0 = (u32)f2bf(acc[m][n][0] + bv) | ((u32)f2bf(acc[m][n][1] + bv) << 16);
        u32 w1 = (u32)f2bf(acc[m][n][2] + bv) | ((u32)f2bf(acc[m][n][3] + bv) << 16);
        *(uint2*)(Vt + ((size_t)(bbi * 12 + hh) * 64 + dd) * 512 + ss) = uint2{w0, w1};
      }
    }
  } else {
    #pragma unroll
    for (int n = 0; n < 4; ++n){
      int gc = col0 + wn * 64 + n * 16 + (lane & 15);
      float bv = bias[gc];
      #pragma unroll
      for (int m = 0; m < 4; ++m){
        int gr = row0 + wm * 64 + m * 16 + (lane >> 4) * 4;
        #pragma unroll
        for (int j = 0; j < 4; ++j){
          float v = acc[m][n][j] + bv;
          if (EPI == 1) v = gelu_f(v);
          ((u16*)Cout)[(size_t)(gr + j) * N + gc] = f2bf(v);
        }
      }
    }
  }
}

// ---------- split-K GEMM: partC[z] = A * Bt^T over K-slice z (no bias) ----------
template<int KSPLIT>
__global__ __launch_bounds__(256, 2)
void gemm_bt_sk(const u16* __restrict__ A, const u16* __restrict__ Bt,
                u16* __restrict__ partC, int M, int N, int K){
  __shared__ u16 lA[2][128 * 64];
  __shared__ u16 lB[2][128 * 64];
  const int tid = threadIdx.x, lane = tid & 63, wv = tid >> 6;
  const int wm = wv >> 1, wn = wv & 1;
  const int gx = gridDim.x, gy = gridDim.y;
  int bid = blockIdx.y * gx + blockIdx.x;
  int xcd = bid & 7, idx = bid >> 3;
  int ch = gy >> 3;
  int bx = idx % gx, by = xcd * ch + idx / gx;
  const int row0 = by * 128, col0 = bx * 128;
  int z = blockIdx.z;
  int ks = K / KSPLIT;
  int kbeg = z * ks;
  auto STAGE = [&](int buf, int k0){
    #pragma unroll
    for (int s = 0; s < 4; ++s){
      int i = s * 256 + tid;
      int r = i >> 3, p = i & 7;
      int sk = k0 + ((p ^ (r & 7)) << 3);
      gload_lds16(A + (size_t)(row0 + r) * K + sk, (char*)lA[buf] + i * 16);
      gload_lds16(Bt + (size_t)(col0 + r) * K + sk, (char*)lB[buf] + i * 16);
    }
  };
  f32x4 acc[4][4] = {};
  const int nt = ks >> 6;
  STAGE(0, kbeg);
  __syncthreads();
  int cur = 0;
  for (int t = 0; t < nt; ++t){
    if (t + 1 < nt) STAGE(cur ^ 1, kbeg + ((t + 1) << 6));
    int g = lane >> 4;
    __builtin_amdgcn_s_setprio(1);
    #pragma unroll
    for (int kk = 0; kk < 2; ++kk){
      bf16x8 af[4], bfv[4];
      #pragma unroll
      for (int m = 0; m < 4; ++m){
        int r = wm * 64 + m * 16 + (lane & 15);
        af[m] = *(const bf16x8*)((const char*)lA[cur] + r * 128 + (((kk * 4 + g) ^ (r & 7)) << 4));
      }
      #pragma unroll
      for (int n = 0; n < 4; ++n){
        int r = wn * 64 + n * 16 + (lane & 15);
        bfv[n] = *(const bf16x8*)((const char*)lB[cur] + r * 128 + (((kk * 4 + g) ^ (r & 7)) << 4));
      }
      #pragma unroll
      for (int m = 0; m < 4; ++m)
        #pragma unroll
        for (int n = 0; n < 4; ++n)
          acc[m][n] = mfma16(af[m], bfv[n], acc[m][n]);
    }
    __builtin_amdgcn_s_setprio(0);
    __syncthreads();
    cur ^= 1;
  }
  u16* Cp = partC + (size_t)z * M * N;
  #pragma unroll
  for (int n = 0; n < 4; ++n){
    int gc = col0 + wn * 64 + n * 16 + (lane & 15);
    #pragma unroll
    for (int m = 0; m < 4; ++m){
      int gr = row0 + wm * 64 + m * 16 + (lane >> 4) * 4;
      #pragma unroll
      for (int j = 0; j < 4; ++j)
        Cp[(size_t)(gr + j) * N + gc] = f2bf(acc[m][n][j]);
    }
  }
}

// ---------- fused attention: S^T = K·Q^T, per-lane softmax, PV ----------
// Double-buffered K/V chunk prefetch; XCD k owns 12 whole heads.
__global__ __launch_bounds__(256, 2) void attn_fused(const u16* __restrict__ qkv,
    const int* __restrict__ amask, const u16* __restrict__ Vt, u16* __restrict__ ctx){
  __shared__ u16 lQ[64 * 64];
  __shared__ u16 lKb[2][128 * 64];   // PV phase: lKb[0] doubles as per-wave P buffers
  __shared__ u16 lVb[2][64 * 128];
  __shared__ float lbias[512];
  int i = (blockIdx.z * gridDim.y + blockIdx.y) * gridDim.x + blockIdx.x;
  int xcd = i & 7, slot = i >> 3;
  int bh = xcd * 12 + (slot >> 3);
  int q0 = (slot & 7) * 64;
  int b = bh / 12, h = bh % 12;
  int tid = threadIdx.x, lane = tid & 63, wv = tid >> 6;
  int q15 = lane & 15, g = lane >> 4;
  const size_t ld = 2304;
  const u16* base = qkv + (size_t)b * 512 * ld + (size_t)h * 64;
  const u16* Vg = Vt + (size_t)(b * 12 + h) * 64 * 512;
  auto stageK = [&](int buf, int c){
    #pragma unroll
    for (int s = 0; s < 4; ++s){
      int ii = s * 256 + tid, r = ii >> 3, p = ii & 7;
      gload_lds16(base + 768 + (size_t)(c * 128 + r) * ld + ((p ^ (r & 7)) << 3),
                  (char*)lKb[buf] + ii * 16);
    }
  };
  auto stageV = [&](int buf, int c){
    #pragma unroll
    for (int s = 0; s < 4; ++s){
      int ii = s * 256 + tid, r = ii >> 4, p = ii & 15;
      gload_lds16(Vg + (size_t)r * 512 + c * 128 + ((p ^ (r & 7)) << 3),
                  (char*)lVb[buf] + ii * 16);
    }
  };
  // prologue: Q + K chunk 0
  #pragma unroll
  for (int s = 0; s < 2; ++s){
    int ii = s * 256 + tid, r = ii >> 3, p = ii & 7;
    gload_lds16(base + (size_t)(q0 + r) * ld + ((p ^ (r & 7)) << 3), (char*)lQ + ii * 16);
  }
  stageK(0, 0);
  for (int ix = tid; ix < 512; ix += 256)
    lbias[ix] = (1.f - (float)amask[(size_t)b * 512 + ix]) * -1e9f;
  f32x4 acc[32];
  #pragma unroll
  for (int ii = 0; ii < 32; ++ii) acc[ii] = {};
  __syncthreads();
  int mr = wv * 16 + q15;
  bf16x8 aq[2];
  #pragma unroll
  for (int ks = 0; ks < 2; ++ks){
    int slog = ks * 4 + g;
    aq[ks] = *(const bf16x8*)((const char*)lQ + mr * 128 + ((slog ^ (mr & 7)) << 4));
  }
  int kcur = 0;
  #pragma unroll
  for (int c = 0; c < 4; ++c){
    if (c + 1 < 4) stageK(kcur ^ 1, c + 1);
    else           stageV(0, 0);         // prefetch V0 under last QK^T chunk
    __builtin_amdgcn_s_setprio(1);
    #pragma unroll
    for (int nf = 0; nf < 8; ++nf){
      int kr = nf * 16 + q15;
      #pragma unroll
      for (int ks = 0; ks < 2; ++ks){
        int slog = ks * 4 + g;
        bf16x8 bk = *(const bf16x8*)((const char*)lKb[kcur] + kr * 128 + ((slog ^ (kr & 7)) << 4));
        acc[c * 8 + nf] = mfma16(bk, aq[ks], acc[c * 8 + nf]);   // C[k][q]
      }
    }
    __builtin_amdgcn_s_setprio(0);
    __syncthreads();
    kcur ^= 1;
  }
  // per-lane softmax: lane owns q = q0+wv*16+q15, k = ii*16 + g*4 + j
  float mx = -3e38f;
  #pragma unroll
  for (int ii = 0; ii < 32; ++ii){
    f32x4 b4 = *(const f32x4*)((const char*)lbias + ii * 64 + g * 16);
    #pragma unroll
    for (int j = 0; j < 4; ++j){
      float v = acc[ii][j] * 0.125f + b4[j];
      acc[ii][j] = v; mx = fmaxf(mx, v);
    }
  }
  mx = fmaxf(mx, __shfl_xor(mx, 16));
  mx = fmaxf(mx, __shfl_xor(mx, 32));
  float sm = 0.f;
  #pragma unroll
  for (int ii = 0; ii < 32; ++ii)
    #pragma unroll
    for (int j = 0; j < 4; ++j){ float p = __expf(acc[ii][j] - mx); acc[ii][j] = p; sm += p; }
  sm += __shfl_xor(sm, 16);
  sm += __shfl_xor(sm, 32);
  float inv = 1.f / sm;
  // PV: double-buffered V chunks; P in per-wave region of lKb[0]
  f32x4 accpv[4] = {};
  char* wvP = (char*)lKb[0] + wv * 4096;
  int vcur = 0;
  #pragma unroll
  for (int c = 0; c < 4; ++c){
    if (c + 1 < 4) stageV(vcur ^ 1, c + 1);
    #pragma unroll
    for (int i2 = 0; i2 < 8; ++i2){
      int ii = c * 8 + i2;
      u32 w0 = (u32)f2bf(acc[ii][0] * inv) | ((u32)f2bf(acc[ii][1] * inv) << 16);
      u32 w1 = (u32)f2bf(acc[ii][2] * inv) | ((u32)f2bf(acc[ii][3] * inv) << 16);
      int slotp = i2 * 2 + (g >> 1);
      char* ad = wvP + q15 * 256 + ((slotp ^ (q15 & 7)) << 4) + ((g & 1) << 3);
      *(uint2*)ad = uint2{w0, w1};
    }
    __builtin_amdgcn_s_setprio(1);
    #pragma unroll
    for (int s = 0; s < 4; ++s){
      bf16x8 pa = *(const bf16x8*)(wvP + q15 * 256 + (((s * 4 + g) ^ (q15 & 7)) << 4));
      #pragma unroll
      for (int nf = 0; nf < 4; ++nf){
        int dr = nf * 16 + q15;
        bf16x8 bv = *(const bf16x8*)((const char*)lVb[vcur] + dr * 256 + (((s * 4 + g) ^ (dr & 7)) << 4));
        accpv[nf] = mfma16(pa, bv, accpv[nf]);
      }
    }
    __builtin_amdgcn_s_setprio(0);
    __syncthreads();
    vcur ^= 1;
  }
  u16* C = ctx + (size_t)b * 512 * 768 + (size_t)h * 64;
  #pragma unroll
  for (int nf = 0; nf < 4; ++nf)
    #pragma unroll
    for (int j = 0; j < 4; ++j){
      int q = q0 + wv * 16 + g * 4 + j;
      int d = nf * 16 + q15;
      C[(size_t)q * 768 + d] = f2bf(accpv[nf][j]);
    }
}

// ---------- emissions: x @ Wt(768x9 f32) + bt -> f32 ----------
__global__ __launch_bounds__(256) void emis_k(const u16* __restrict__ xb,
    const float* __restrict__ Wt, const float* __restrict__ bt, float* __restrict__ emis){
  int row = blockIdx.x * 4 + (threadIdx.x >> 6);
  int lane = threadIdx.x & 63;
  float a[9] = {};
  #pragma unroll
  for (int j = 0; j < 12; ++j){
    int k = lane + j * 64;
    float xv = bf2f(xb[(size_t)row * 768 + k]);
    #pragma unroll
    for (int t = 0; t < 9; ++t) a[t] += xv * Wt[(size_t)k * 9 + t];
  }
  #pragma unroll
  for (int o = 1; o < 64; o <<= 1)
    #pragma unroll
    for (int t = 0; t < 9; ++t) a[t] += __shfl_xor(a[t], o);
  if (lane == 0){
    #pragma unroll
    for (int t = 0; t < 9; ++t) emis[(size_t)row * 9 + t] = a[t] + bt[t];
  }
}

// ---------- CRF chunk products: log-semiring 9x9 matrix scan ----------
__global__ __launch_bounds__(128) void crf_chunk(const float* __restrict__ emis,
    const int* __restrict__ amask, const float* __restrict__ ctrans,
    float* __restrict__ chunkP){
  __shared__ float cur[2][96];
  int blk = blockIdx.x; int b = blk >> 4, c = blk & 15;
  int t0 = threadIdx.x;
  bool act = t0 < 81;
  int tc = act ? t0 : 0;
  int i = tc / 9, j = tc - i * 9;
  float tr[9];
  #pragma unroll
  for (int k = 0; k < 9; ++k) tr[k] = ctrans[k * 9 + j];
  const float* eb = emis + (size_t)b * 512 * 9;
  const int* mb = amask + (size_t)b * 512;
  int lo = c * 32 + (c == 0 ? 1 : 0), hi = c * 32 + 31;
  if (act){
    int m = mb[lo];
    cur[0][t0] = m ? (ctrans[i * 9 + j] + eb[(size_t)lo * 9 + j])
                   : (i == j ? 0.f : -1e30f);
  }
  __syncthreads();
  int pp = 0;
  for (int t = lo + 1; t <= hi; ++t){
    float a[9];
    #pragma unroll
    for (int k = 0; k < 9; ++k) a[k] = cur[pp][i * 9 + k];
    int m = mb[t];
    float outv;
    if (m){
      float ej = eb[(size_t)t * 9 + j];
      float mm = -3e38f;
      #pragma unroll
      for (int k = 0; k < 9; ++k){ a[k] += tr[k]; mm = fmaxf(mm, a[k]); }
      float ss = 0.f;
      #pragma unroll
      for (int k = 0; k < 9; ++k) ss += __expf(a[k] - mm);
      outv = ej + mm + __logf(ss);
    } else {
      outv = a[j];
    }
    if (act) cur[pp ^ 1][t0] = outv;
    __syncthreads();
    pp ^= 1;
  }
  if (act) chunkP[(size_t)(b * 16 + c) * 81 + t0] = cur[pp][t0];
}

// ---------- CRF final: numerator + apply chunk products + combine ----------
__global__ __launch_bounds__(128) void crf_final(const float* __restrict__ emis,
    const int* __restrict__ labels, const int* __restrict__ amask,
    const float* __restrict__ cstart, const float* __restrict__ cend,
    const float* __restrict__ ctrans, const float* __restrict__ chunkP,
    float* __restrict__ out){
  __shared__ float numb[8], denb[8];
  int tid = threadIdx.x;
  { // numerator
    int b = tid >> 4, gg = tid & 15;
    const int* lab = labels + (size_t)b * 512;
    const int* msk = amask + (size_t)b * 512;
    float part = 0.f; int cnt = 0;
    for (int i = gg; i < 512; i += 16){
      int m = msk[i]; cnt += m;
      if (i >= 1){
        int tp = lab[i - 1], tcc = lab[i];
        part += (ctrans[tp * 9 + tcc] + emis[((size_t)b * 512 + i) * 9 + tcc]) * (float)m;
      }
    }
    #pragma unroll
    for (int o = 1; o < 16; o <<= 1){ part += __shfl_xor(part, o); cnt += __shfl_xor(cnt, o); }
    if (gg == 0){
      int tt0 = lab[0];
      numb[b] = part + cstart[tt0] + emis[((size_t)b * 512) * 9 + tt0] + cend[lab[cnt - 1]];
    }
  }
  __syncthreads();
  { // denominator via 16 chunk products
    int lane = tid & 63, w = tid >> 6;
    int sub = lane >> 4, j = lane & 15;
    int b = w * 4 + sub;
    bool act = j < 9;
    int jj = act ? j : 0;
    int gbase = lane & 48;
    float alpha = cstart[jj] + emis[(size_t)b * 512 * 9 + jj];
    for (int c = 0; c < 16; ++c){
      const float* P = chunkP + (size_t)(b * 16 + c) * 81;
      float av[9];
      #pragma unroll
      for (int k = 0; k < 9; ++k) av[k] = __shfl(alpha, gbase + k) + P[k * 9 + jj];
      float mm = -3e38f;
      #pragma unroll
      for (int k = 0; k < 9; ++k) mm = fmaxf(mm, av[k]);
      float ss = 0.f;
      #pragma unroll
      for (int k = 0; k < 9; ++k) ss += __expf(av[k] - mm);
      alpha = mm + __logf(ss);
    }
    float v = alpha + cend[jj];
    float av[9];
    #pragma unroll
    for (int k = 0; k < 9; ++k) av[k] = __shfl(v, gbase + k);
    float mm = -3e38f;
    #pragma unroll
    for (int k = 0; k < 9; ++k) mm = fmaxf(mm, av[k]);
    float ss = 0.f;
    #pragma unroll
    for (int k = 0; k < 9; ++k) ss += __expf(av[k] - mm);
    if (act && j == 0) denb[b] = mm + __logf(ss);
  }
  __syncthreads();
  if (tid == 0){
    float s = 0.f;
    #pragma unroll
    for (int b = 0; b < 8; ++b) s += numb[b] - denb[b];
    out[0] = -(s * 0.125f);
  }
}

// ---------- host ----------
extern "C" void kernel_launch(void* const* d_in, const int* in_sizes, int n_in,
                              void* d_out, int out_size, void* d_ws, size_t ws_size,
                              hipStream_t stream){
  const int*   input_ids = (const int*)d_in[0];
  const int*   amask     = (const int*)d_in[1];
  const int*   ttids     = (const int*)d_in[2];
  const int*   labels    = (const int*)d_in[3];
  const float* word_emb  = (const float*)d_in[4];
  const float* pos_emb   = (const float*)d_in[5];
  const float* type_emb  = (const float*)d_in[6];
  const float* eln_s     = (const float*)d_in[7];
  const float* eln_b     = (const float*)d_in[8];
  const float* Wqkv      = (const float*)d_in[9];
  const float* bqkv      = (const float*)d_in[10];
  const float* Wo        = (const float*)d_in[11];
  const float* bo        = (const float*)d_in[12];
  const float* ln1s      = (const float*)d_in[13];
  const float* ln1b      = (const float*)d_in[14];
  const float* W1        = (const float*)d_in[15];
  const float* b1        = (const float*)d_in[16];
  const float* W2        = (const float*)d_in[17];
  const float* b2        = (const float*)d_in[18];
  const float* ln2s      = (const float*)d_in[19];
  const float* ln2b      = (const float*)d_in[20];
  const float* Wt        = (const float*)d_in[21];
  const float* bt        = (const float*)d_in[22];
  const float* cstart    = (const float*)d_in[23];
  const float* cend      = (const float*)d_in[24];
  const float* ctrans    = (const float*)d_in[25];

  char* w = (char*)d_ws;
  auto alloc = [&](size_t sz){ char* p = w; w += (sz + 255) & ~(size_t)255; return p; };
  u16*   xb     = (u16*)  alloc(4096ULL * 768 * 2);
  u16*   qkvb   = (u16*)  alloc(4096ULL * 2304 * 2);
  u16*   ctxb   = (u16*)  alloc(4096ULL * 768 * 2);
  u16*   hb     = (u16*)  alloc(4096ULL * 3072 * 2);
  u16*   Vtb    = (u16*)  alloc(96ULL * 64 * 512 * 2);
  u16*   pbuf   = (u16*)  alloc(4ULL * 4096 * 768 * 2);
  u16*   Wqkv_b = (u16*)  alloc(12ULL * 2304 * 768 * 2);
  u16*   Wo_b   = (u16*)  alloc(12ULL * 768 * 768 * 2);
  u16*   W1_b   = (u16*)  alloc(12ULL * 3072 * 768 * 2);
  u16*   W2_b   = (u16*)  alloc(12ULL * 768 * 3072 * 2);
  float* emis   = (float*)alloc(8ULL * 512 * 9 * 4);
  float* chunkP = (float*)alloc(8ULL * 16 * 81 * 4);
  (void)ws_size; (void)in_sizes; (void)n_in; (void)out_size;

  embed_ln<<<1024, 256, 0, stream>>>(input_ids, ttids, word_emb, pos_emb, type_emb,
                                     eln_s, eln_b, xb);
  transcvt_l<<<dim3(72, 24, 12), 256, 0, stream>>>(Wqkv, Wqkv_b, 768, 2304);
  transcvt_l<<<dim3(24, 24, 12), 256, 0, stream>>>(Wo, Wo_b, 768, 768);
  transcvt_l<<<dim3(96, 24, 12), 256, 0, stream>>>(W1, W1_b, 768, 3072);
  transcvt_l<<<dim3(24, 96, 12), 256, 0, stream>>>(W2, W2_b, 3072, 768);

  for (int l = 0; l < 12; ++l){
    gemm_bt<3, 2><<<dim3(18, 32), 256, 0, stream>>>(xb, Wqkv_b + (size_t)l * 2304 * 768,
        bqkv + (size_t)l * 2304, qkvb, Vtb, 4096, 2304, 768);
    attn_fused<<<dim3(8, 12, 8), 256, 0, stream>>>(qkvb, amask, Vtb, ctxb);
    gemm_bt_sk<2><<<dim3(6, 32, 2), 256, 0, stream>>>(ctxb, Wo_b + (size_t)l * 768 * 768,
        pbuf, 4096, 768, 768);
    res_ln_p<2><<<1024, 256, 0, stream>>>(pbuf, xb, bo + (size_t)l * 768,
        ln1s + (size_t)l * 768, ln1b + (size_t)l * 768, xb);
    gemm_bt<1, 2><<<dim3(24, 32), 256, 0, stream>>>(xb, W1_b + (size_t)l * 3072 * 768,
        b1 + (size_t)l * 3072, hb, nullptr, 4096, 3072, 768);
    gemm_bt_sk<4><<<dim3(6, 32, 4), 256, 0, stream>>>(hb, W2_b + (size_t)l * 768 * 3072,
        pbuf, 4096, 768, 3072);
    res_ln_p<4><<<1024, 256, 0, stream>>>(pbuf, xb, b2 + (size_t)l * 768,
        ln2s + (size_t)l * 768, ln2b + (size_t)l * 768, xb);
  }
  emis_k<<<1024, 256, 0, stream>>>(xb, Wt, bt, emis);
  crf_chunk<<<128, 128, 0, stream>>>(emis, amask, ctrans, chunkP);
  crf_final<<<1, 128, 0, stream>>>(emis, labels, amask, cstart, cend, ctrans, chunkP,
                                   (float*)d_out);
}

// Round 7
// 1835.344 us; speedup vs baseline: 1.0806x; 1.0806x over previous
//
#include <hip/hip_runtime.h>
#include <math.h>

typedef unsigned short u16;
typedef unsigned int u32;
typedef __bf16 bf16x8 __attribute__((ext_vector_type(8)));
typedef float f32x4 __attribute__((ext_vector_type(4)));

// ---------- helpers ----------
__device__ __forceinline__ u16 f2bf(float f){
  unsigned u = __float_as_uint(f);
  unsigned r = u + 0x7fffu + ((u >> 16) & 1u);
  return (u16)(r >> 16);
}
__device__ __forceinline__ float bf2f(u16 h){ return __uint_as_float(((unsigned)h) << 16); }

__device__ __forceinline__ void gload_lds16(const void* g, void* l){
  __builtin_amdgcn_global_load_lds(
      (__attribute__((address_space(1))) void*)(g),
      (__attribute__((address_space(3))) void*)(l), 16, 0, 0);
}
__device__ __forceinline__ f32x4 mfma16(bf16x8 a, bf16x8 b, f32x4 c){
  return __builtin_amdgcn_mfma_f32_16x16x32_bf16(a, b, c, 0, 0, 0);
}
__device__ __forceinline__ float gelu_f(float x){
  float a = 0.7978845608028654f * (x + 0.044715f * x * x * x);
  a = fminf(fmaxf(a, -15.f), 15.f);
  float t = __expf(2.f * a);
  return 0.5f * x * (1.f + (t - 1.f) / (t + 1.f));
}

// ---------- transpose + f32->bf16 convert: W[l][K][N] -> Wt[l][N][K] ----------
__global__ __launch_bounds__(256) void transcvt_l(const float* __restrict__ W,
                                                  u16* __restrict__ Wt, int K, int N){
  int l = blockIdx.z;
  W  += (size_t)l * K * N;
  Wt += (size_t)l * N * K;
  __shared__ float tile[32][33];
  int tx = threadIdx.x & 31, ty = threadIdx.x >> 5;
  int n0 = blockIdx.x * 32, k0 = blockIdx.y * 32;
  #pragma unroll
  for (int j = 0; j < 32; j += 8)
    tile[ty + j][tx] = W[(size_t)(k0 + ty + j) * N + n0 + tx];
  __syncthreads();
  #pragma unroll
  for (int j = 0; j < 32; j += 8)
    Wt[(size_t)(n0 + ty + j) * K + k0 + tx] = f2bf(tile[tx][ty + j]);
}

// ---------- embedding + layernorm -> bf16 x ----------
__global__ __launch_bounds__(256) void embed_ln(const int* __restrict__ ids,
    const int* __restrict__ tts, const float* __restrict__ we, const float* __restrict__ pe,
    const float* __restrict__ te, const float* __restrict__ g, const float* __restrict__ bb,
    u16* __restrict__ xb){
  int tok = blockIdx.x * 4 + (threadIdx.x >> 6);
  int lane = threadIdx.x & 63;
  int s = tok & 511;
  int id = ids[tok], tt = tts[tok];
  float e[12]; float sum = 0.f, sq = 0.f;
  #pragma unroll
  for (int j = 0; j < 12; ++j){
    int c = lane + j * 64;
    float v = we[(size_t)id * 768 + c] + pe[(size_t)s * 768 + c] + te[(size_t)tt * 768 + c];
    e[j] = v; sum += v; sq += v * v;
  }
  #pragma unroll
  for (int o = 1; o < 64; o <<= 1){ sum += __shfl_xor(sum, o); sq += __shfl_xor(sq, o); }
  float mean = sum * (1.f / 768.f);
  float var = sq * (1.f / 768.f) - mean * mean;
  float inv = rsqrtf(var + 1e-12f);
  size_t base = (size_t)tok * 768;
  #pragma unroll
  for (int j = 0; j < 12; ++j){
    int c = lane + j * 64;
    xb[base + c] = f2bf((e[j] - mean) * inv * g[c] + bb[c]);
  }
}

// ---------- partial-sum + bias + residual + layernorm ----------
template<int P>
__global__ __launch_bounds__(256) void res_ln_p(const u16* __restrict__ parts,
    const u16* __restrict__ res, const float* __restrict__ bias,
    const float* __restrict__ g, const float* __restrict__ bb, u16* __restrict__ xout){
  int tok = blockIdx.x * 4 + (threadIdx.x >> 6);
  int lane = threadIdx.x & 63;
  size_t base = (size_t)tok * 768;
  const size_t MN = 4096ULL * 768;
  float v[12]; float sum = 0.f, sq = 0.f;
  #pragma unroll
  for (int j = 0; j < 3; ++j){
    int c = j * 256 + lane * 4;
    ushort4 r = *(const ushort4*)(res + base + c);
    f32x4 bsv = *(const f32x4*)(bias + c);
    const u16* rp = (const u16*)&r;
    float f[4];
    #pragma unroll
    for (int e = 0; e < 4; ++e) f[e] = bf2f(rp[e]) + bsv[e];
    #pragma unroll
    for (int p = 0; p < P; ++p){
      ushort4 a = *(const ushort4*)(parts + p * MN + base + c);
      const u16* ap = (const u16*)&a;
      #pragma unroll
      for (int e = 0; e < 4; ++e) f[e] += bf2f(ap[e]);
    }
    #pragma unroll
    for (int e = 0; e < 4; ++e){
      v[j * 4 + e] = f[e]; sum += f[e]; sq += f[e] * f[e];
    }
  }
  #pragma unroll
  for (int o = 1; o < 64; o <<= 1){ sum += __shfl_xor(sum, o); sq += __shfl_xor(sq, o); }
  float mean = sum * (1.f / 768.f);
  float var = sq * (1.f / 768.f) - mean * mean;
  float inv = rsqrtf(var + 1e-12f);
  #pragma unroll
  for (int j = 0; j < 3; ++j){
    int c = j * 256 + lane * 4;
    f32x4 gs = *(const f32x4*)(g + c);
    f32x4 bs = *(const f32x4*)(bb + c);
    ushort4 o; u16* op = (u16*)&o;
    #pragma unroll
    for (int e = 0; e < 4; ++e)
      op[e] = f2bf((v[j * 4 + e] - mean) * inv * gs[e] + bs[e]);
    *(ushort4*)(xout + base + c) = o;
  }
}

// ---------- GEMM: C = A[M][K](bf16) * Bt[N][K]^T (bf16) + bias ----------
// BK=32, DOUBLE-BUFFERED (2 x 16 KB = 32 KB LDS, same occupancy as single-buffer
// BK=64). Prefetch of tile t+1 issued before MFMA on tile t; the single
// end-of-step __syncthreads (vmcnt(0)) drains it after compute.
// EPI 1: gelu -> bf16 ; EPI 3: QKV (Q,K -> Cout; V -> Cout2 transposed [bh][d][s])
template<int EPI, int XSPLIT>
__global__ __launch_bounds__(256, 2)
void gemm_bt(const u16* __restrict__ A, const u16* __restrict__ Bt,
             const float* __restrict__ bias, void* __restrict__ Cout,
             void* __restrict__ Cout2, int M, int N, int K){
  __shared__ u16 lA[2][128 * 32];
  __shared__ u16 lB[2][128 * 32];
  const int tid = threadIdx.x, lane = tid & 63, wv = tid >> 6;
  const int wm = wv >> 1, wn = wv & 1;
  const int gx = gridDim.x, gy = gridDim.y;
  int bid = blockIdx.y * gx + blockIdx.x;
  int xcd = bid & 7, idx = bid >> 3;
  int bx, by;
  if (XSPLIT == 2){
    int cw = gx >> 1, ch = gy >> 2;
    bx = (xcd >> 2) * cw + idx % cw;
    by = (xcd & 3) * ch + idx / cw;
  } else {
    int ch = gy >> 3;
    bx = idx % gx;
    by = xcd * ch + idx / gx;
  }
  const int row0 = by * 128, col0 = bx * 128;
  auto STAGE = [&](int buf, int k0){
    #pragma unroll
    for (int s = 0; s < 2; ++s){
      int i = s * 256 + tid;
      int r = i >> 2, p = i & 3;
      int sk = k0 + ((p ^ ((r >> 1) & 3)) << 3);
      gload_lds16(A + (size_t)(row0 + r) * K + sk, (char*)lA[buf] + i * 16);
      gload_lds16(Bt + (size_t)(col0 + r) * K + sk, (char*)lB[buf] + i * 16);
    }
  };
  int aoff[4], boff[4];
  #pragma unroll
  for (int m = 0; m < 4; ++m){
    int r = wm * 64 + m * 16 + (lane & 15);
    int p = (lane >> 4) ^ ((r >> 1) & 3);
    aoff[m] = r * 64 + p * 16;
  }
  #pragma unroll
  for (int n = 0; n < 4; ++n){
    int r = wn * 64 + n * 16 + (lane & 15);
    int p = (lane >> 4) ^ ((r >> 1) & 3);
    boff[n] = r * 64 + p * 16;
  }
  f32x4 acc[4][4] = {};
  const int nt = K >> 5;
  STAGE(0, 0);
  __syncthreads();
  int cur = 0;
  for (int t = 0; t < nt; ++t){
    if (t + 1 < nt) STAGE(cur ^ 1, (t + 1) << 5);
    __builtin_amdgcn_s_setprio(1);
    bf16x8 af[4], bfv[4];
    #pragma unroll
    for (int m = 0; m < 4; ++m) af[m] = *(const bf16x8*)((const char*)lA[cur] + aoff[m]);
    #pragma unroll
    for (int n = 0; n < 4; ++n) bfv[n] = *(const bf16x8*)((const char*)lB[cur] + boff[n]);
    #pragma unroll
    for (int m = 0; m < 4; ++m)
      #pragma unroll
      for (int n = 0; n < 4; ++n)
        acc[m][n] = mfma16(af[m], bfv[n], acc[m][n]);
    __builtin_amdgcn_s_setprio(0);
    __syncthreads();
    cur ^= 1;
  }
  if (EPI == 3 && col0 >= 1536){
    u16* Vt = (u16*)Cout2;
    #pragma unroll
    for (int n = 0; n < 4; ++n){
      int gc = col0 + wn * 64 + n * 16 + (lane & 15);
      float bv = bias[gc];
      int vcol = gc - 1536, hh = vcol >> 6, dd = vcol & 63;
      #pragma unroll
      for (int m = 0; m < 4; ++m){
        int gr = row0 + wm * 64 + m * 16 + (lane >> 4) * 4;
        int bbi = gr >> 9, ss = gr & 511;
        u32 w0 = (u32)f2bf(acc[m][n][0] + bv) | ((u32)f2bf(acc[m][n][1] + bv) << 16);
        u32 w1 = (u32)f2bf(acc[m][n][2] + bv) | ((u32)f2bf(acc[m][n][3] + bv) << 16);
        *(uint2*)(Vt + ((size_t)(bbi * 12 + hh) * 64 + dd) * 512 + ss) = uint2{w0, w1};
      }
    }
  } else {
    #pragma unroll
    for (int n = 0; n < 4; ++n){
      int gc = col0 + wn * 64 + n * 16 + (lane & 15);
      float bv = bias[gc];
      #pragma unroll
      for (int m = 0; m < 4; ++m){
        int gr = row0 + wm * 64 + m * 16 + (lane >> 4) * 4;
        #pragma unroll
        for (int j = 0; j < 4; ++j){
          float v = acc[m][n][j] + bv;
          if (EPI == 1) v = gelu_f(v);
          ((u16*)Cout)[(size_t)(gr + j) * N + gc] = f2bf(v);
        }
      }
    }
  }
}

// ---------- split-K GEMM: partC[z] = A * Bt^T over K-slice z (no bias) ----------
template<int KSPLIT>
__global__ __launch_bounds__(256, 2)
void gemm_bt_sk(const u16* __restrict__ A, const u16* __restrict__ Bt,
                u16* __restrict__ partC, int M, int N, int K){
  __shared__ u16 lA[2][128 * 32];
  __shared__ u16 lB[2][128 * 32];
  const int tid = threadIdx.x, lane = tid & 63, wv = tid >> 6;
  const int wm = wv >> 1, wn = wv & 1;
  const int gx = gridDim.x, gy = gridDim.y;
  int bid = blockIdx.y * gx + blockIdx.x;
  int xcd = bid & 7, idx = bid >> 3;
  int ch = gy >> 3;
  int bx = idx % gx, by = xcd * ch + idx / gx;
  const int row0 = by * 128, col0 = bx * 128;
  int z = blockIdx.z;
  int ks = K / KSPLIT;
  int kbeg = z * ks;
  auto STAGE = [&](int buf, int k0){
    #pragma unroll
    for (int s = 0; s < 2; ++s){
      int i = s * 256 + tid;
      int r = i >> 2, p = i & 3;
      int sk = k0 + ((p ^ ((r >> 1) & 3)) << 3);
      gload_lds16(A + (size_t)(row0 + r) * K + sk, (char*)lA[buf] + i * 16);
      gload_lds16(Bt + (size_t)(col0 + r) * K + sk, (char*)lB[buf] + i * 16);
    }
  };
  int aoff[4], boff[4];
  #pragma unroll
  for (int m = 0; m < 4; ++m){
    int r = wm * 64 + m * 16 + (lane & 15);
    int p = (lane >> 4) ^ ((r >> 1) & 3);
    aoff[m] = r * 64 + p * 16;
  }
  #pragma unroll
  for (int n = 0; n < 4; ++n){
    int r = wn * 64 + n * 16 + (lane & 15);
    int p = (lane >> 4) ^ ((r >> 1) & 3);
    boff[n] = r * 64 + p * 16;
  }
  f32x4 acc[4][4] = {};
  const int nt = ks >> 5;
  STAGE(0, kbeg);
  __syncthreads();
  int cur = 0;
  for (int t = 0; t < nt; ++t){
    if (t + 1 < nt) STAGE(cur ^ 1, kbeg + ((t + 1) << 5));
    __builtin_amdgcn_s_setprio(1);
    bf16x8 af[4], bfv[4];
    #pragma unroll
    for (int m = 0; m < 4; ++m) af[m] = *(const bf16x8*)((const char*)lA[cur] + aoff[m]);
    #pragma unroll
    for (int n = 0; n < 4; ++n) bfv[n] = *(const bf16x8*)((const char*)lB[cur] + boff[n]);
    #pragma unroll
    for (int m = 0; m < 4; ++m)
      #pragma unroll
      for (int n = 0; n < 4; ++n)
        acc[m][n] = mfma16(af[m], bfv[n], acc[m][n]);
    __builtin_amdgcn_s_setprio(0);
    __syncthreads();
    cur ^= 1;
  }
  u16* Cp = partC + (size_t)z * M * N;
  #pragma unroll
  for (int n = 0; n < 4; ++n){
    int gc = col0 + wn * 64 + n * 16 + (lane & 15);
    #pragma unroll
    for (int m = 0; m < 4; ++m){
      int gr = row0 + wm * 64 + m * 16 + (lane >> 4) * 4;
      #pragma unroll
      for (int j = 0; j < 4; ++j)
        Cp[(size_t)(gr + j) * N + gc] = f2bf(acc[m][n][j]);
    }
  }
}

// ---------- fused attention: S^T = K·Q^T, per-lane softmax, PV ----------
// (R5 configuration: single K/V buffers, 42 KB LDS, 3 blocks/CU.)
__global__ __launch_bounds__(256, 2) void attn_fused(const u16* __restrict__ qkv,
    const int* __restrict__ amask, const u16* __restrict__ Vt, u16* __restrict__ ctx){
  __shared__ u16 lQ[64 * 64];
  __shared__ u16 lK[128 * 64];   // scores phase: K chunk; PV phase: per-wave P buffers
  __shared__ u16 lV[64 * 128];
  __shared__ float lbias[512];
  int i = (blockIdx.z * gridDim.y + blockIdx.y) * gridDim.x + blockIdx.x;
  int xcd = i & 7, slot = i >> 3;
  int bh = xcd * 12 + (slot >> 3);
  int q0 = (slot & 7) * 64;
  int b = bh / 12, h = bh % 12;
  int tid = threadIdx.x, lane = tid & 63, wv = tid >> 6;
  int q15 = lane & 15, g = lane >> 4;
  const size_t ld = 2304;
  const u16* base = qkv + (size_t)b * 512 * ld + (size_t)h * 64;
  #pragma unroll
  for (int s = 0; s < 2; ++s){
    int ii = s * 256 + tid, r = ii >> 3, p = ii & 7;
    gload_lds16(base + (size_t)(q0 + r) * ld + ((p ^ (r & 7)) << 3), (char*)lQ + ii * 16);
  }
  for (int ix = tid; ix < 512; ix += 256)
    lbias[ix] = (1.f - (float)amask[(size_t)b * 512 + ix]) * -1e9f;
  f32x4 acc[32];
  #pragma unroll
  for (int ii = 0; ii < 32; ++ii) acc[ii] = {};
  int mr = wv * 16 + q15;
  bf16x8 aq[2];
  #pragma unroll
  for (int c = 0; c < 4; ++c){
    #pragma unroll
    for (int s = 0; s < 4; ++s){
      int ii = s * 256 + tid, r = ii >> 3, p = ii & 7;
      gload_lds16(base + 768 + (size_t)(c * 128 + r) * ld + ((p ^ (r & 7)) << 3),
                  (char*)lK + ii * 16);
    }
    __syncthreads();
    if (c == 0){
      #pragma unroll
      for (int ks = 0; ks < 2; ++ks){
        int slog = ks * 4 + g;
        aq[ks] = *(const bf16x8*)((const char*)lQ + mr * 128 + ((slog ^ (mr & 7)) << 4));
      }
    }
    __builtin_amdgcn_s_setprio(1);
    #pragma unroll
    for (int nf = 0; nf < 8; ++nf){
      int kr = nf * 16 + q15;
      #pragma unroll
      for (int ks = 0; ks < 2; ++ks){
        int slog = ks * 4 + g;
        bf16x8 bk = *(const bf16x8*)((const char*)lK + kr * 128 + ((slog ^ (kr & 7)) << 4));
        acc[c * 8 + nf] = mfma16(bk, aq[ks], acc[c * 8 + nf]);   // C[k][q]
      }
    }
    __builtin_amdgcn_s_setprio(0);
    __syncthreads();
  }
  // per-lane softmax: lane owns q = q0+wv*16+q15, k = ii*16 + g*4 + j
  float mx = -3e38f;
  #pragma unroll
  for (int ii = 0; ii < 32; ++ii){
    f32x4 b4 = *(const f32x4*)((const char*)lbias + ii * 64 + g * 16);
    #pragma unroll
    for (int j = 0; j < 4; ++j){
      float v = acc[ii][j] * 0.125f + b4[j];
      acc[ii][j] = v; mx = fmaxf(mx, v);
    }
  }
  mx = fmaxf(mx, __shfl_xor(mx, 16));
  mx = fmaxf(mx, __shfl_xor(mx, 32));
  float sm = 0.f;
  #pragma unroll
  for (int ii = 0; ii < 32; ++ii)
    #pragma unroll
    for (int j = 0; j < 4; ++j){ float p = __expf(acc[ii][j] - mx); acc[ii][j] = p; sm += p; }
  sm += __shfl_xor(sm, 16);
  sm += __shfl_xor(sm, 32);
  float inv = 1.f / sm;
  // PV
  const u16* Vg = Vt + (size_t)(b * 12 + h) * 64 * 512;
  f32x4 accpv[4] = {};
  char* wvP = (char*)lK + wv * 4096;   // per-wave 16q x 128k bf16, XOR-swizzled
  #pragma unroll
  for (int c = 0; c < 4; ++c){
    #pragma unroll
    for (int s = 0; s < 4; ++s){
      int ii = s * 256 + tid, r = ii >> 4, p = ii & 15;
      gload_lds16(Vg + (size_t)r * 512 + c * 128 + ((p ^ (r & 7)) << 3), (char*)lV + ii * 16);
    }
    #pragma unroll
    for (int i2 = 0; i2 < 8; ++i2){
      int ii = c * 8 + i2;
      u32 w0 = (u32)f2bf(acc[ii][0] * inv) | ((u32)f2bf(acc[ii][1] * inv) << 16);
      u32 w1 = (u32)f2bf(acc[ii][2] * inv) | ((u32)f2bf(acc[ii][3] * inv) << 16);
      int slotp = i2 * 2 + (g >> 1);
      char* ad = wvP + q15 * 256 + ((slotp ^ (q15 & 7)) << 4) + ((g & 1) << 3);
      *(uint2*)ad = uint2{w0, w1};
    }
    __syncthreads();
    __builtin_amdgcn_s_setprio(1);
    #pragma unroll
    for (int s = 0; s < 4; ++s){
      bf16x8 pa = *(const bf16x8*)(wvP + q15 * 256 + (((s * 4 + g) ^ (q15 & 7)) << 4));
      #pragma unroll
      for (int nf = 0; nf < 4; ++nf){
        int dr = nf * 16 + q15;
        bf16x8 bv = *(const bf16x8*)((const char*)lV + dr * 256 + (((s * 4 + g) ^ (dr & 7)) << 4));
        accpv[nf] = mfma16(pa, bv, accpv[nf]);
      }
    }
    __builtin_amdgcn_s_setprio(0);
    __syncthreads();
  }
  u16* C = ctx + (size_t)b * 512 * 768 + (size_t)h * 64;
  #pragma unroll
  for (int nf = 0; nf < 4; ++nf)
    #pragma unroll
    for (int j = 0; j < 4; ++j){
      int q = q0 + wv * 16 + g * 4 + j;
      int d = nf * 16 + q15;
      C[(size_t)q * 768 + d] = f2bf(accpv[nf][j]);
    }
}

// ---------- emissions: x @ Wt(768x9 f32) + bt -> f32 ----------
__global__ __launch_bounds__(256) void emis_k(const u16* __restrict__ xb,
    const float* __restrict__ Wt, const float* __restrict__ bt, float* __restrict__ emis){
  int row = blockIdx.x * 4 + (threadIdx.x >> 6);
  int lane = threadIdx.x & 63;
  float a[9] = {};
  #pragma unroll
  for (int j = 0; j < 12; ++j){
    int k = lane + j * 64;
    float xv = bf2f(xb[(size_t)row * 768 + k]);
    #pragma unroll
    for (int t = 0; t < 9; ++t) a[t] += xv * Wt[(size_t)k * 9 + t];
  }
  #pragma unroll
  for (int o = 1; o < 64; o <<= 1)
    #pragma unroll
    for (int t = 0; t < 9; ++t) a[t] += __shfl_xor(a[t], o);
  if (lane == 0){
    #pragma unroll
    for (int t = 0; t < 9; ++t) emis[(size_t)row * 9 + t] = a[t] + bt[t];
  }
}

// ---------- CRF chunk products: log-semiring 9x9 matrix scan ----------
__global__ __launch_bounds__(128) void crf_chunk(const float* __restrict__ emis,
    const int* __restrict__ amask, const float* __restrict__ ctrans,
    float* __restrict__ chunkP){
  __shared__ float cur[2][96];
  int blk = blockIdx.x; int b = blk >> 4, c = blk & 15;
  int t0 = threadIdx.x;
  bool act = t0 < 81;
  int tc = act ? t0 : 0;
  int i = tc / 9, j = tc - i * 9;
  float tr[9];
  #pragma unroll
  for (int k = 0; k < 9; ++k) tr[k] = ctrans[k * 9 + j];
  const float* eb = emis + (size_t)b * 512 * 9;
  const int* mb = amask + (size_t)b * 512;
  int lo = c * 32 + (c == 0 ? 1 : 0), hi = c * 32 + 31;
  if (act){
    int m = mb[lo];
    cur[0][t0] = m ? (ctrans[i * 9 + j] + eb[(size_t)lo * 9 + j])
                   : (i == j ? 0.f : -1e30f);
  }
  __syncthreads();
  int pp = 0;
  for (int t = lo + 1; t <= hi; ++t){
    float a[9];
    #pragma unroll
    for (int k = 0; k < 9; ++k) a[k] = cur[pp][i * 9 + k];
    int m = mb[t];
    float outv;
    if (m){
      float ej = eb[(size_t)t * 9 + j];
      float mm = -3e38f;
      #pragma unroll
      for (int k = 0; k < 9; ++k){ a[k] += tr[k]; mm = fmaxf(mm, a[k]); }
      float ss = 0.f;
      #pragma unroll
      for (int k = 0; k < 9; ++k) ss += __expf(a[k] - mm);
      outv = ej + mm + __logf(ss);
    } else {
      outv = a[j];
    }
    if (act) cur[pp ^ 1][t0] = outv;
    __syncthreads();
    pp ^= 1;
  }
  if (act) chunkP[(size_t)(b * 16 + c) * 81 + t0] = cur[pp][t0];
}

// ---------- CRF final: numerator + apply chunk products + combine ----------
__global__ __launch_bounds__(128) void crf_final(const float* __restrict__ emis,
    const int* __restrict__ labels, const int* __restrict__ amask,
    const float* __restrict__ cstart, const float* __restrict__ cend,
    const float* __restrict__ ctrans, const float* __restrict__ chunkP,
    float* __restrict__ out){
  __shared__ float numb[8], denb[8];
  int tid = threadIdx.x;
  { // numerator
    int b = tid >> 4, gg = tid & 15;
    const int* lab = labels + (size_t)b * 512;
    const int* msk = amask + (size_t)b * 512;
    float part = 0.f; int cnt = 0;
    for (int i = gg; i < 512; i += 16){
      int m = msk[i]; cnt += m;
      if (i >= 1){
        int tp = lab[i - 1], tcc = lab[i];
        part += (ctrans[tp * 9 + tcc] + emis[((size_t)b * 512 + i) * 9 + tcc]) * (float)m;
      }
    }
    #pragma unroll
    for (int o = 1; o < 16; o <<= 1){ part += __shfl_xor(part, o); cnt += __shfl_xor(cnt, o); }
    if (gg == 0){
      int tt0 = lab[0];
      numb[b] = part + cstart[tt0] + emis[((size_t)b * 512) * 9 + tt0] + cend[lab[cnt - 1]];
    }
  }
  __syncthreads();
  { // denominator via 16 chunk products
    int lane = tid & 63, w = tid >> 6;
    int sub = lane >> 4, j = lane & 15;
    int b = w * 4 + sub;
    bool act = j < 9;
    int jj = act ? j : 0;
    int gbase = lane & 48;
    float alpha = cstart[jj] + emis[(size_t)b * 512 * 9 + jj];
    for (int c = 0; c < 16; ++c){
      const float* P = chunkP + (size_t)(b * 16 + c) * 81;
      float av[9];
      #pragma unroll
      for (int k = 0; k < 9; ++k) av[k] = __shfl(alpha, gbase + k) + P[k * 9 + jj];
      float mm = -3e38f;
      #pragma unroll
      for (int k = 0; k < 9; ++k) mm = fmaxf(mm, av[k]);
      float ss = 0.f;
      #pragma unroll
      for (int k = 0; k < 9; ++k) ss += __expf(av[k] - mm);
      alpha = mm + __logf(ss);
    }
    float v = alpha + cend[jj];
    float av[9];
    #pragma unroll
    for (int k = 0; k < 9; ++k) av[k] = __shfl(v, gbase + k);
    float mm = -3e38f;
    #pragma unroll
    for (int k = 0; k < 9; ++k) mm = fmaxf(mm, av[k]);
    float ss = 0.f;
    #pragma unroll
    for (int k = 0; k < 9; ++k) ss += __expf(av[k] - mm);
    if (act && j == 0) denb[b] = mm + __logf(ss);
  }
  __syncthreads();
  if (tid == 0){
    float s = 0.f;
    #pragma unroll
    for (int b = 0; b < 8; ++b) s += numb[b] - denb[b];
    out[0] = -(s * 0.125f);
  }
}

// ---------- host ----------
extern "C" void kernel_launch(void* const* d_in, const int* in_sizes, int n_in,
                              void* d_out, int out_size, void* d_ws, size_t ws_size,
                              hipStream_t stream){
  const int*   input_ids = (const int*)d_in[0];
  const int*   amask     = (const int*)d_in[1];
  const int*   ttids     = (const int*)d_in[2];
  const int*   labels    = (const int*)d_in[3];
  const float* word_emb  = (const float*)d_in[4];
  const float* pos_emb   = (const float*)d_in[5];
  const float* type_emb  = (const float*)d_in[6];
  const float* eln_s     = (const float*)d_in[7];
  const float* eln_b     = (const float*)d_in[8];
  const float* Wqkv      = (const float*)d_in[9];
  const float* bqkv      = (const float*)d_in[10];
  const float* Wo        = (const float*)d_in[11];
  const float* bo        = (const float*)d_in[12];
  const float* ln1s      = (const float*)d_in[13];
  const float* ln1b      = (const float*)d_in[14];
  const float* W1        = (const float*)d_in[15];
  const float* b1        = (const float*)d_in[16];
  const float* W2        = (const float*)d_in[17];
  const float* b2        = (const float*)d_in[18];
  const float* ln2s      = (const float*)d_in[19];
  const float* ln2b      = (const float*)d_in[20];
  const float* Wt        = (const float*)d_in[21];
  const float* bt        = (const float*)d_in[22];
  const float* cstart    = (const float*)d_in[23];
  const float* cend      = (const float*)d_in[24];
  const float* ctrans    = (const float*)d_in[25];

  char* w = (char*)d_ws;
  auto alloc = [&](size_t sz){ char* p = w; w += (sz + 255) & ~(size_t)255; return p; };
  u16*   xb     = (u16*)  alloc(4096ULL * 768 * 2);
  u16*   qkvb   = (u16*)  alloc(4096ULL * 2304 * 2);
  u16*   ctxb   = (u16*)  alloc(4096ULL * 768 * 2);
  u16*   hb     = (u16*)  alloc(4096ULL * 3072 * 2);
  u16*   Vtb    = (u16*)  alloc(96ULL * 64 * 512 * 2);
  u16*   pbuf   = (u16*)  alloc(4ULL * 4096 * 768 * 2);
  u16*   Wqkv_b = (u16*)  alloc(12ULL * 2304 * 768 * 2);
  u16*   Wo_b   = (u16*)  alloc(12ULL * 768 * 768 * 2);
  u16*   W1_b   = (u16*)  alloc(12ULL * 3072 * 768 * 2);
  u16*   W2_b   = (u16*)  alloc(12ULL * 768 * 3072 * 2);
  float* emis   = (float*)alloc(8ULL * 512 * 9 * 4);
  float* chunkP = (float*)alloc(8ULL * 16 * 81 * 4);
  (void)ws_size; (void)in_sizes; (void)n_in; (void)out_size;

  embed_ln<<<1024, 256, 0, stream>>>(input_ids, ttids, word_emb, pos_emb, type_emb,
                                     eln_s, eln_b, xb);
  transcvt_l<<<dim3(72, 24, 12), 256, 0, stream>>>(Wqkv, Wqkv_b, 768, 2304);
  transcvt_l<<<dim3(24, 24, 12), 256, 0, stream>>>(Wo, Wo_b, 768, 768);
  transcvt_l<<<dim3(96, 24, 12), 256, 0, stream>>>(W1, W1_b, 768, 3072);
  transcvt_l<<<dim3(24, 96, 12), 256, 0, stream>>>(W2, W2_b, 3072, 768);

  for (int l = 0; l < 12; ++l){
    gemm_bt<3, 2><<<dim3(18, 32), 256, 0, stream>>>(xb, Wqkv_b + (size_t)l * 2304 * 768,
        bqkv + (size_t)l * 2304, qkvb, Vtb, 4096, 2304, 768);
    attn_fused<<<dim3(8, 12, 8), 256, 0, stream>>>(qkvb, amask, Vtb, ctxb);
    gemm_bt_sk<2><<<dim3(6, 32, 2), 256, 0, stream>>>(ctxb, Wo_b + (size_t)l * 768 * 768,
        pbuf, 4096, 768, 768);
    res_ln_p<2><<<1024, 256, 0, stream>>>(pbuf, xb, bo + (size_t)l * 768,
        ln1s + (size_t)l * 768, ln1b + (size_t)l * 768, xb);
    gemm_bt<1, 2><<<dim3(24, 32), 256, 0, stream>>>(xb, W1_b + (size_t)l * 3072 * 768,
        b1 + (size_t)l * 3072, hb, nullptr, 4096, 3072, 768);
    gemm_bt_sk<4><<<dim3(6, 32, 4), 256, 0, stream>>>(hb, W2_b + (size_t)l * 768 * 3072,
        pbuf, 4096, 768, 3072);
    res_ln_p<4><<<1024, 256, 0, stream>>>(pbuf, xb, b2 + (size_t)l * 768,
        ln2s + (size_t)l * 768, ln2b + (size_t)l * 768, xb);
  }
  emis_k<<<1024, 256, 0, stream>>>(xb, Wt, bt, emis);
  crf_chunk<<<128, 128, 0, stream>>>(emis, amask, ctrans, chunkP);
  crf_final<<<1, 128, 0, stream>>>(emis, labels, amask, cstart, cend, ctrans, chunkP,
                                   (float*)d_out);
}

// Round 8
// 1686.618 us; speedup vs baseline: 1.1759x; 1.0882x over previous
//
#include <hip/hip_runtime.h>
#include <math.h>

typedef unsigned short u16;
typedef unsigned char u8;
typedef unsigned int u32;
typedef __bf16 bf16x8 __attribute__((ext_vector_type(8)));
typedef float f32x4 __attribute__((ext_vector_type(4)));

// ---------- helpers ----------
__device__ __forceinline__ u16 f2bf(float f){
  unsigned u = __float_as_uint(f);
  unsigned r = u + 0x7fffu + ((u >> 16) & 1u);
  return (u16)(r >> 16);
}
__device__ __forceinline__ float bf2f(u16 h){ return __uint_as_float(((unsigned)h) << 16); }
__device__ __forceinline__ u8 f2fp8(float v){
  int w = __builtin_amdgcn_cvt_pk_fp8_f32(v, v, 0, false);
  return (u8)(w & 0xff);
}

__device__ __forceinline__ void gload_lds16(const void* g, void* l){
  __builtin_amdgcn_global_load_lds(
      (__attribute__((address_space(1))) void*)(g),
      (__attribute__((address_space(3))) void*)(l), 16, 0, 0);
}
__device__ __forceinline__ f32x4 mfma16(bf16x8 a, bf16x8 b, f32x4 c){
  return __builtin_amdgcn_mfma_f32_16x16x32_bf16(a, b, c, 0, 0, 0);
}
__device__ __forceinline__ f32x4 mfma8(long a, long b, f32x4 c){
  return __builtin_amdgcn_mfma_f32_16x16x32_fp8_fp8(a, b, c, 0, 0, 0);
}
__device__ __forceinline__ float gelu_f(float x){
  float a = 0.7978845608028654f * (x + 0.044715f * x * x * x);
  a = fminf(fmaxf(a, -15.f), 15.f);
  float t = __expf(2.f * a);
  return 0.5f * x * (1.f + (t - 1.f) / (t + 1.f));
}

// ---------- transpose + f32->bf16 convert: W[l][K][N] -> Wt[l][N][K] ----------
__global__ __launch_bounds__(256) void transcvt_l(const float* __restrict__ W,
                                                  u16* __restrict__ Wt, int K, int N){
  int l = blockIdx.z;
  W  += (size_t)l * K * N;
  Wt += (size_t)l * N * K;
  __shared__ float tile[32][33];
  int tx = threadIdx.x & 31, ty = threadIdx.x >> 5;
  int n0 = blockIdx.x * 32, k0 = blockIdx.y * 32;
  #pragma unroll
  for (int j = 0; j < 32; j += 8)
    tile[ty + j][tx] = W[(size_t)(k0 + ty + j) * N + n0 + tx];
  __syncthreads();
  #pragma unroll
  for (int j = 0; j < 32; j += 8)
    Wt[(size_t)(n0 + ty + j) * K + k0 + tx] = f2bf(tile[tx][ty + j]);
}

// ---------- transpose + f32->fp8(x16) convert: W[l][K][N] -> W8[l][N][K] ----------
__global__ __launch_bounds__(256) void transcvt8_l(const float* __restrict__ W,
                                                   u8* __restrict__ W8, int K, int N){
  int l = blockIdx.z;
  W  += (size_t)l * K * N;
  W8 += (size_t)l * N * K;
  __shared__ float tile[32][33];
  int tx = threadIdx.x & 31, ty = threadIdx.x >> 5;
  int n0 = blockIdx.x * 32, k0 = blockIdx.y * 32;
  #pragma unroll
  for (int j = 0; j < 32; j += 8)
    tile[ty + j][tx] = W[(size_t)(k0 + ty + j) * N + n0 + tx];
  __syncthreads();
  #pragma unroll
  for (int j = 0; j < 32; j += 8)
    W8[(size_t)(n0 + ty + j) * K + k0 + tx] = f2fp8(tile[tx][ty + j] * 16.f);
}

// ---------- embedding + layernorm -> bf16 x ----------
__global__ __launch_bounds__(256) void embed_ln(const int* __restrict__ ids,
    const int* __restrict__ tts, const float* __restrict__ we, const float* __restrict__ pe,
    const float* __restrict__ te, const float* __restrict__ g, const float* __restrict__ bb,
    u16* __restrict__ xb){
  int tok = blockIdx.x * 4 + (threadIdx.x >> 6);
  int lane = threadIdx.x & 63;
  int s = tok & 511;
  int id = ids[tok], tt = tts[tok];
  float e[12]; float sum = 0.f, sq = 0.f;
  #pragma unroll
  for (int j = 0; j < 12; ++j){
    int c = lane + j * 64;
    float v = we[(size_t)id * 768 + c] + pe[(size_t)s * 768 + c] + te[(size_t)tt * 768 + c];
    e[j] = v; sum += v; sq += v * v;
  }
  #pragma unroll
  for (int o = 1; o < 64; o <<= 1){ sum += __shfl_xor(sum, o); sq += __shfl_xor(sq, o); }
  float mean = sum * (1.f / 768.f);
  float var = sq * (1.f / 768.f) - mean * mean;
  float inv = rsqrtf(var + 1e-12f);
  size_t base = (size_t)tok * 768;
  #pragma unroll
  for (int j = 0; j < 12; ++j){
    int c = lane + j * 64;
    xb[base + c] = f2bf((e[j] - mean) * inv * g[c] + bb[c]);
  }
}

// ---------- partial-sum + bias + residual + layernorm (opt. fp8 copy out) ----------
template<int P, int F8>
__global__ __launch_bounds__(256) void res_ln_p(const u16* __restrict__ parts,
    const u16* __restrict__ res, const float* __restrict__ bias,
    const float* __restrict__ g, const float* __restrict__ bb, u16* __restrict__ xout,
    u8* __restrict__ x8out){
  int tok = blockIdx.x * 4 + (threadIdx.x >> 6);
  int lane = threadIdx.x & 63;
  size_t base = (size_t)tok * 768;
  const size_t MN = 4096ULL * 768;
  float v[12]; float sum = 0.f, sq = 0.f;
  #pragma unroll
  for (int j = 0; j < 3; ++j){
    int c = j * 256 + lane * 4;
    ushort4 r = *(const ushort4*)(res + base + c);
    f32x4 bsv = *(const f32x4*)(bias + c);
    const u16* rp = (const u16*)&r;
    float f[4];
    #pragma unroll
    for (int e = 0; e < 4; ++e) f[e] = bf2f(rp[e]) + bsv[e];
    #pragma unroll
    for (int p = 0; p < P; ++p){
      ushort4 a = *(const ushort4*)(parts + p * MN + base + c);
      const u16* ap = (const u16*)&a;
      #pragma unroll
      for (int e = 0; e < 4; ++e) f[e] += bf2f(ap[e]);
    }
    #pragma unroll
    for (int e = 0; e < 4; ++e){
      v[j * 4 + e] = f[e]; sum += f[e]; sq += f[e] * f[e];
    }
  }
  #pragma unroll
  for (int o = 1; o < 64; o <<= 1){ sum += __shfl_xor(sum, o); sq += __shfl_xor(sq, o); }
  float mean = sum * (1.f / 768.f);
  float var = sq * (1.f / 768.f) - mean * mean;
  float inv = rsqrtf(var + 1e-12f);
  #pragma unroll
  for (int j = 0; j < 3; ++j){
    int c = j * 256 + lane * 4;
    f32x4 gs = *(const f32x4*)(g + c);
    f32x4 bs = *(const f32x4*)(bb + c);
    float vv[4];
    ushort4 o; u16* op = (u16*)&o;
    #pragma unroll
    for (int e = 0; e < 4; ++e){
      vv[e] = (v[j * 4 + e] - mean) * inv * gs[e] + bs[e];
      op[e] = f2bf(vv[e]);
    }
    *(ushort4*)(xout + base + c) = o;
    if (F8){
      int lo = __builtin_amdgcn_cvt_pk_fp8_f32(vv[0], vv[1], 0, false);
      int w  = __builtin_amdgcn_cvt_pk_fp8_f32(vv[2], vv[3], lo, true);
      *(u32*)(x8out + base + c) = (u32)w;
    }
  }
}

// ---------- GEMM bf16 (R5 config): BK=64 single-buffer, 2 barriers/step ----------
// EPI 1: gelu -> bf16 ; EPI 3: QKV (Q,K -> Cout; V -> Cout2 transposed [bh][d][s])
template<int EPI, int XSPLIT>
__global__ __launch_bounds__(256, 2)
void gemm_bt(const u16* __restrict__ A, const u16* __restrict__ Bt,
             const float* __restrict__ bias, void* __restrict__ Cout,
             void* __restrict__ Cout2, int M, int N, int K){
  __shared__ u16 lA[128 * 64];
  __shared__ u16 lB[128 * 64];
  const int tid = threadIdx.x, lane = tid & 63, wv = tid >> 6;
  const int wm = wv >> 1, wn = wv & 1;
  const int gx = gridDim.x, gy = gridDim.y;
  int bid = blockIdx.y * gx + blockIdx.x;
  int xcd = bid & 7, idx = bid >> 3;
  int bx, by;
  if (XSPLIT == 2){
    int cw = gx >> 1, ch = gy >> 2;
    bx = (xcd >> 2) * cw + idx % cw;
    by = (xcd & 3) * ch + idx / cw;
  } else {
    int ch = gy >> 3;
    bx = idx % gx;
    by = xcd * ch + idx / gx;
  }
  const int row0 = by * 128, col0 = bx * 128;
  f32x4 acc[4][4] = {};
  for (int k0 = 0; k0 < K; k0 += 64){
    #pragma unroll
    for (int s = 0; s < 4; ++s){
      int i = s * 256 + tid;
      int r = i >> 3, p = i & 7;
      int sk = k0 + ((p ^ (r & 7)) << 3);
      gload_lds16(A + (size_t)(row0 + r) * K + sk, (char*)lA + i * 16);
      gload_lds16(Bt + (size_t)(col0 + r) * K + sk, (char*)lB + i * 16);
    }
    __syncthreads();
    int g = lane >> 4;
    #pragma unroll
    for (int kk = 0; kk < 2; ++kk){
      bf16x8 af[4], bfv[4];
      #pragma unroll
      for (int m = 0; m < 4; ++m){
        int r = wm * 64 + m * 16 + (lane & 15);
        af[m] = *(const bf16x8*)((const char*)lA + r * 128 + (((kk * 4 + g) ^ (r & 7)) << 4));
      }
      #pragma unroll
      for (int n = 0; n < 4; ++n){
        int r = wn * 64 + n * 16 + (lane & 15);
        bfv[n] = *(const bf16x8*)((const char*)lB + r * 128 + (((kk * 4 + g) ^ (r & 7)) << 4));
      }
      #pragma unroll
      for (int m = 0; m < 4; ++m)
        #pragma unroll
        for (int n = 0; n < 4; ++n)
          acc[m][n] = mfma16(af[m], bfv[n], acc[m][n]);
    }
    __syncthreads();
  }
  if (EPI == 3 && col0 >= 1536){
    u16* Vt = (u16*)Cout2;
    #pragma unroll
    for (int n = 0; n < 4; ++n){
      int gc = col0 + wn * 64 + n * 16 + (lane & 15);
      float bv = bias[gc];
      int vcol = gc - 1536, hh = vcol >> 6, dd = vcol & 63;
      #pragma unroll
      for (int m = 0; m < 4; ++m){
        int gr = row0 + wm * 64 + m * 16 + (lane >> 4) * 4;
        int bbi = gr >> 9, ss = gr & 511;
        u32 w0 = (u32)f2bf(acc[m][n][0] + bv) | ((u32)f2bf(acc[m][n][1] + bv) << 16);
        u32 w1 = (u32)f2bf(acc[m][n][2] + bv) | ((u32)f2bf(acc[m][n][3] + bv) << 16);
        *(uint2*)(Vt + ((size_t)(bbi * 12 + hh) * 64 + dd) * 512 + ss) = uint2{w0, w1};
      }
    }
  } else {
    #pragma unroll
    for (int n = 0; n < 4; ++n){
      int gc = col0 + wn * 64 + n * 16 + (lane & 15);
      float bv = bias[gc];
      #pragma unroll
      for (int m = 0; m < 4; ++m){
        int gr = row0 + wm * 64 + m * 16 + (lane >> 4) * 4;
        #pragma unroll
        for (int j = 0; j < 4; ++j){
          float v = acc[m][n][j] + bv;
          if (EPI == 1) v = gelu_f(v);
          ((u16*)Cout)[(size_t)(gr + j) * N + gc] = f2bf(v);
        }
      }
    }
  }
}

// ---------- split-K GEMM bf16 (Wo): partC[z] = A * Bt^T over K-slice z ----------
template<int KSPLIT>
__global__ __launch_bounds__(256, 2)
void gemm_bt_sk(const u16* __restrict__ A, const u16* __restrict__ Bt,
                u16* __restrict__ partC, int M, int N, int K){
  __shared__ u16 lA[128 * 64];
  __shared__ u16 lB[128 * 64];
  const int tid = threadIdx.x, lane = tid & 63, wv = tid >> 6;
  const int wm = wv >> 1, wn = wv & 1;
  const int gx = gridDim.x, gy = gridDim.y;
  int bid = blockIdx.y * gx + blockIdx.x;
  int xcd = bid & 7, idx = bid >> 3;
  int ch = gy >> 3;
  int bx = idx % gx, by = xcd * ch + idx / gx;
  const int row0 = by * 128, col0 = bx * 128;
  int z = blockIdx.z;
  int ks = K / KSPLIT;
  int kbeg = z * ks, kend = kbeg + ks;
  f32x4 acc[4][4] = {};
  for (int k0 = kbeg; k0 < kend; k0 += 64){
    #pragma unroll
    for (int s = 0; s < 4; ++s){
      int i = s * 256 + tid;
      int r = i >> 3, p = i & 7;
      int sk = k0 + ((p ^ (r & 7)) << 3);
      gload_lds16(A + (size_t)(row0 + r) * K + sk, (char*)lA + i * 16);
      gload_lds16(Bt + (size_t)(col0 + r) * K + sk, (char*)lB + i * 16);
    }
    __syncthreads();
    int g = lane >> 4;
    #pragma unroll
    for (int kk = 0; kk < 2; ++kk){
      bf16x8 af[4], bfv[4];
      #pragma unroll
      for (int m = 0; m < 4; ++m){
        int r = wm * 64 + m * 16 + (lane & 15);
        af[m] = *(const bf16x8*)((const char*)lA + r * 128 + (((kk * 4 + g) ^ (r & 7)) << 4));
      }
      #pragma unroll
      for (int n = 0; n < 4; ++n){
        int r = wn * 64 + n * 16 + (lane & 15);
        bfv[n] = *(const bf16x8*)((const char*)lB + r * 128 + (((kk * 4 + g) ^ (r & 7)) << 4));
      }
      #pragma unroll
      for (int m = 0; m < 4; ++m)
        #pragma unroll
        for (int n = 0; n < 4; ++n)
          acc[m][n] = mfma16(af[m], bfv[n], acc[m][n]);
    }
    __syncthreads();
  }
  u16* Cp = partC + (size_t)z * M * N;
  #pragma unroll
  for (int n = 0; n < 4; ++n){
    int gc = col0 + wn * 64 + n * 16 + (lane & 15);
    #pragma unroll
    for (int m = 0; m < 4; ++m){
      int gr = row0 + wm * 64 + m * 16 + (lane >> 4) * 4;
      #pragma unroll
      for (int j = 0; j < 4; ++j)
        Cp[(size_t)(gr + j) * N + gc] = f2bf(acc[m][n][j]);
    }
  }
}

// ---------- fp8 GEMM: C = A8[M][K] * B8t[N][K]^T, weights pre-scaled x16 ----------
// BK=64, single-buffer (16 KB LDS). EPI 1: (acc/16+bias)->gelu->fp8
// EPI 2: (acc/16)->bf16 partials at z*M*N
template<int EPI, int XSPLIT, int KSPLIT>
__global__ __launch_bounds__(256, 2)
void gemm8(const u8* __restrict__ A, const u8* __restrict__ Bt,
           const float* __restrict__ bias, void* __restrict__ Cout,
           int M, int N, int K){
  __shared__ u8 lA[128 * 64];
  __shared__ u8 lB[128 * 64];
  const int tid = threadIdx.x, lane = tid & 63, wv = tid >> 6;
  const int wm = wv >> 1, wn = wv & 1;
  const int gx = gridDim.x, gy = gridDim.y;
  int bid = blockIdx.y * gx + blockIdx.x;
  int xcd = bid & 7, idx = bid >> 3;
  int bx, by;
  if (XSPLIT == 2){
    int cw = gx >> 1, ch = gy >> 2;
    bx = (xcd >> 2) * cw + idx % cw;
    by = (xcd & 3) * ch + idx / cw;
  } else {
    int ch = gy >> 3;
    bx = idx % gx;
    by = xcd * ch + idx / gx;
  }
  const int row0 = by * 128, col0 = bx * 128;
  int z = (KSPLIT > 1) ? blockIdx.z : 0;
  int ks = K / KSPLIT;
  int kbeg = z * ks, kend = kbeg + ks;
  f32x4 acc[4][4] = {};
  for (int k0 = kbeg; k0 < kend; k0 += 64){
    // stage 128 rows x 64 B each for A and B; 16B chunk c of row r sourced from
    // chunk c^(r&3) so ds_read slot s reads s^((r&3)<<1) (pair-preserving XOR)
    #pragma unroll
    for (int s = 0; s < 2; ++s){
      int i = s * 256 + tid;
      int r = i >> 2, c = i & 3;
      int sk = k0 + ((c ^ (r & 3)) << 4);
      gload_lds16(A + (size_t)(row0 + r) * K + sk, (char*)lA + i * 16);
      gload_lds16(Bt + (size_t)(col0 + r) * K + sk, (char*)lB + i * 16);
    }
    __syncthreads();
    int g = lane >> 4;
    #pragma unroll
    for (int kk = 0; kk < 2; ++kk){
      long af[4], bfv[4];
      #pragma unroll
      for (int m = 0; m < 4; ++m){
        int r = wm * 64 + m * 16 + (lane & 15);
        af[m] = *(const long*)((const char*)lA + r * 64 + (((kk * 4 + g) ^ ((r & 3) << 1)) << 3));
      }
      #pragma unroll
      for (int n = 0; n < 4; ++n){
        int r = wn * 64 + n * 16 + (lane & 15);
        bfv[n] = *(const long*)((const char*)lB + r * 64 + (((kk * 4 + g) ^ ((r & 3) << 1)) << 3));
      }
      #pragma unroll
      for (int m = 0; m < 4; ++m)
        #pragma unroll
        for (int n = 0; n < 4; ++n)
          acc[m][n] = mfma8(af[m], bfv[n], acc[m][n]);
    }
    __syncthreads();
  }
  if (EPI == 1){
    #pragma unroll
    for (int n = 0; n < 4; ++n){
      int gc = col0 + wn * 64 + n * 16 + (lane & 15);
      float bv = bias[gc];
      #pragma unroll
      for (int m = 0; m < 4; ++m){
        int gr = row0 + wm * 64 + m * 16 + (lane >> 4) * 4;
        #pragma unroll
        for (int j = 0; j < 4; ++j){
          float v = gelu_f(acc[m][n][j] * 0.0625f + bv);
          ((u8*)Cout)[(size_t)(gr + j) * N + gc] = f2fp8(v);
        }
      }
    }
  } else {
    u16* Cp = (u16*)Cout + (size_t)z * M * N;
    #pragma unroll
    for (int n = 0; n < 4; ++n){
      int gc = col0 + wn * 64 + n * 16 + (lane & 15);
      #pragma unroll
      for (int m = 0; m < 4; ++m){
        int gr = row0 + wm * 64 + m * 16 + (lane >> 4) * 4;
        #pragma unroll
        for (int j = 0; j < 4; ++j)
          Cp[(size_t)(gr + j) * N + gc] = f2bf(acc[m][n][j] * 0.0625f);
      }
    }
  }
}

// ---------- fused attention (R5 config) ----------
__global__ __launch_bounds__(256, 2) void attn_fused(const u16* __restrict__ qkv,
    const int* __restrict__ amask, const u16* __restrict__ Vt, u16* __restrict__ ctx){
  __shared__ u16 lQ[64 * 64];
  __shared__ u16 lK[128 * 64];
  __shared__ u16 lV[64 * 128];
  __shared__ float lbias[512];
  int i = (blockIdx.z * gridDim.y + blockIdx.y) * gridDim.x + blockIdx.x;
  int xcd = i & 7, slot = i >> 3;
  int bh = xcd * 12 + (slot >> 3);
  int q0 = (slot & 7) * 64;
  int b = bh / 12, h = bh % 12;
  int tid = threadIdx.x, lane = tid & 63, wv = tid >> 6;
  int q15 = lane & 15, g = lane >> 4;
  const size_t ld = 2304;
  const u16* base = qkv + (size_t)b * 512 * ld + (size_t)h * 64;
  #pragma unroll
  for (int s = 0; s < 2; ++s){
    int ii = s * 256 + tid, r = ii >> 3, p = ii & 7;
    gload_lds16(base + (size_t)(q0 + r) * ld + ((p ^ (r & 7)) << 3), (char*)lQ + ii * 16);
  }
  for (int ix = tid; ix < 512; ix += 256)
    lbias[ix] = (1.f - (float)amask[(size_t)b * 512 + ix]) * -1e9f;
  f32x4 acc[32];
  #pragma unroll
  for (int ii = 0; ii < 32; ++ii) acc[ii] = {};
  int mr = wv * 16 + q15;
  bf16x8 aq[2];
  #pragma unroll
  for (int c = 0; c < 4; ++c){
    #pragma unroll
    for (int s = 0; s < 4; ++s){
      int ii = s * 256 + tid, r = ii >> 3, p = ii & 7;
      gload_lds16(base + 768 + (size_t)(c * 128 + r) * ld + ((p ^ (r & 7)) << 3),
                  (char*)lK + ii * 16);
    }
    __syncthreads();
    if (c == 0){
      #pragma unroll
      for (int ks = 0; ks < 2; ++ks){
        int slog = ks * 4 + g;
        aq[ks] = *(const bf16x8*)((const char*)lQ + mr * 128 + ((slog ^ (mr & 7)) << 4));
      }
    }
    __builtin_amdgcn_s_setprio(1);
    #pragma unroll
    for (int nf = 0; nf < 8; ++nf){
      int kr = nf * 16 + q15;
      #pragma unroll
      for (int ks = 0; ks < 2; ++ks){
        int slog = ks * 4 + g;
        bf16x8 bk = *(const bf16x8*)((const char*)lK + kr * 128 + ((slog ^ (kr & 7)) << 4));
        acc[c * 8 + nf] = mfma16(bk, aq[ks], acc[c * 8 + nf]);   // C[k][q]
      }
    }
    __builtin_amdgcn_s_setprio(0);
    __syncthreads();
  }
  float mx = -3e38f;
  #pragma unroll
  for (int ii = 0; ii < 32; ++ii){
    f32x4 b4 = *(const f32x4*)((const char*)lbias + ii * 64 + g * 16);
    #pragma unroll
    for (int j = 0; j < 4; ++j){
      float v = acc[ii][j] * 0.125f + b4[j];
      acc[ii][j] = v; mx = fmaxf(mx, v);
    }
  }
  mx = fmaxf(mx, __shfl_xor(mx, 16));
  mx = fmaxf(mx, __shfl_xor(mx, 32));
  float sm = 0.f;
  #pragma unroll
  for (int ii = 0; ii < 32; ++ii)
    #pragma unroll
    for (int j = 0; j < 4; ++j){ float p = __expf(acc[ii][j] - mx); acc[ii][j] = p; sm += p; }
  sm += __shfl_xor(sm, 16);
  sm += __shfl_xor(sm, 32);
  float inv = 1.f / sm;
  const u16* Vg = Vt + (size_t)(b * 12 + h) * 64 * 512;
  f32x4 accpv[4] = {};
  char* wvP = (char*)lK + wv * 4096;
  #pragma unroll
  for (int c = 0; c < 4; ++c){
    #pragma unroll
    for (int s = 0; s < 4; ++s){
      int ii = s * 256 + tid, r = ii >> 4, p = ii & 15;
      gload_lds16(Vg + (size_t)r * 512 + c * 128 + ((p ^ (r & 7)) << 3), (char*)lV + ii * 16);
    }
    #pragma unroll
    for (int i2 = 0; i2 < 8; ++i2){
      int ii = c * 8 + i2;
      u32 w0 = (u32)f2bf(acc[ii][0] * inv) | ((u32)f2bf(acc[ii][1] * inv) << 16);
      u32 w1 = (u32)f2bf(acc[ii][2] * inv) | ((u32)f2bf(acc[ii][3] * inv) << 16);
      int slotp = i2 * 2 + (g >> 1);
      char* ad = wvP + q15 * 256 + ((slotp ^ (q15 & 7)) << 4) + ((g & 1) << 3);
      *(uint2*)ad = uint2{w0, w1};
    }
    __syncthreads();
    __builtin_amdgcn_s_setprio(1);
    #pragma unroll
    for (int s = 0; s < 4; ++s){
      bf16x8 pa = *(const bf16x8*)(wvP + q15 * 256 + (((s * 4 + g) ^ (q15 & 7)) << 4));
      #pragma unroll
      for (int nf = 0; nf < 4; ++nf){
        int dr = nf * 16 + q15;
        bf16x8 bv = *(const bf16x8*)((const char*)lV + dr * 256 + (((s * 4 + g) ^ (dr & 7)) << 4));
        accpv[nf] = mfma16(pa, bv, accpv[nf]);
      }
    }
    __builtin_amdgcn_s_setprio(0);
    __syncthreads();
  }
  u16* C = ctx + (size_t)b * 512 * 768 + (size_t)h * 64;
  #pragma unroll
  for (int nf = 0; nf < 4; ++nf)
    #pragma unroll
    for (int j = 0; j < 4; ++j){
      int q = q0 + wv * 16 + g * 4 + j;
      int d = nf * 16 + q15;
      C[(size_t)q * 768 + d] = f2bf(accpv[nf][j]);
    }
}

// ---------- emissions: x @ Wt(768x9 f32) + bt -> f32 ----------
__global__ __launch_bounds__(256) void emis_k(const u16* __restrict__ xb,
    const float* __restrict__ Wt, const float* __restrict__ bt, float* __restrict__ emis){
  int row = blockIdx.x * 4 + (threadIdx.x >> 6);
  int lane = threadIdx.x & 63;
  float a[9] = {};
  #pragma unroll
  for (int j = 0; j < 12; ++j){
    int k = lane + j * 64;
    float xv = bf2f(xb[(size_t)row * 768 + k]);
    #pragma unroll
    for (int t = 0; t < 9; ++t) a[t] += xv * Wt[(size_t)k * 9 + t];
  }
  #pragma unroll
  for (int o = 1; o < 64; o <<= 1)
    #pragma unroll
    for (int t = 0; t < 9; ++t) a[t] += __shfl_xor(a[t], o);
  if (lane == 0){
    #pragma unroll
    for (int t = 0; t < 9; ++t) emis[(size_t)row * 9 + t] = a[t] + bt[t];
  }
}

// ---------- CRF chunk products: log-semiring 9x9 matrix scan ----------
__global__ __launch_bounds__(128) void crf_chunk(const float* __restrict__ emis,
    const int* __restrict__ amask, const float* __restrict__ ctrans,
    float* __restrict__ chunkP){
  __shared__ float cur[2][96];
  int blk = blockIdx.x; int b = blk >> 4, c = blk & 15;
  int t0 = threadIdx.x;
  bool act = t0 < 81;
  int tc = act ? t0 : 0;
  int i = tc / 9, j = tc - i * 9;
  float tr[9];
  #pragma unroll
  for (int k = 0; k < 9; ++k) tr[k] = ctrans[k * 9 + j];
  const float* eb = emis + (size_t)b * 512 * 9;
  const int* mb = amask + (size_t)b * 512;
  int lo = c * 32 + (c == 0 ? 1 : 0), hi = c * 32 + 31;
  if (act){
    int m = mb[lo];
    cur[0][t0] = m ? (ctrans[i * 9 + j] + eb[(size_t)lo * 9 + j])
                   : (i == j ? 0.f : -1e30f);
  }
  __syncthreads();
  int pp = 0;
  for (int t = lo + 1; t <= hi; ++t){
    float a[9];
    #pragma unroll
    for (int k = 0; k < 9; ++k) a[k] = cur[pp][i * 9 + k];
    int m = mb[t];
    float outv;
    if (m){
      float ej = eb[(size_t)t * 9 + j];
      float mm = -3e38f;
      #pragma unroll
      for (int k = 0; k < 9; ++k){ a[k] += tr[k]; mm = fmaxf(mm, a[k]); }
      float ss = 0.f;
      #pragma unroll
      for (int k = 0; k < 9; ++k) ss += __expf(a[k] - mm);
      outv = ej + mm + __logf(ss);
    } else {
      outv = a[j];
    }
    if (act) cur[pp ^ 1][t0] = outv;
    __syncthreads();
    pp ^= 1;
  }
  if (act) chunkP[(size_t)(b * 16 + c) * 81 + t0] = cur[pp][t0];
}

// ---------- CRF final ----------
__global__ __launch_bounds__(128) void crf_final(const float* __restrict__ emis,
    const int* __restrict__ labels, const int* __restrict__ amask,
    const float* __restrict__ cstart, const float* __restrict__ cend,
    const float* __restrict__ ctrans, const float* __restrict__ chunkP,
    float* __restrict__ out){
  __shared__ float numb[8], denb[8];
  int tid = threadIdx.x;
  {
    int b = tid >> 4, gg = tid & 15;
    const int* lab = labels + (size_t)b * 512;
    const int* msk = amask + (size_t)b * 512;
    float part = 0.f; int cnt = 0;
    for (int i = gg; i < 512; i += 16){
      int m = msk[i]; cnt += m;
      if (i >= 1){
        int tp = lab[i - 1], tcc = lab[i];
        part += (ctrans[tp * 9 + tcc] + emis[((size_t)b * 512 + i) * 9 + tcc]) * (float)m;
      }
    }
    #pragma unroll
    for (int o = 1; o < 16; o <<= 1){ part += __shfl_xor(part, o); cnt += __shfl_xor(cnt, o); }
    if (gg == 0){
      int tt0 = lab[0];
      numb[b] = part + cstart[tt0] + emis[((size_t)b * 512) * 9 + tt0] + cend[lab[cnt - 1]];
    }
  }
  __syncthreads();
  {
    int lane = tid & 63, w = tid >> 6;
    int sub = lane >> 4, j = lane & 15;
    int b = w * 4 + sub;
    bool act = j < 9;
    int jj = act ? j : 0;
    int gbase = lane & 48;
    float alpha = cstart[jj] + emis[(size_t)b * 512 * 9 + jj];
    for (int c = 0; c < 16; ++c){
      const float* P = chunkP + (size_t)(b * 16 + c) * 81;
      float av[9];
      #pragma unroll
      for (int k = 0; k < 9; ++k) av[k] = __shfl(alpha, gbase + k) + P[k * 9 + jj];
      float mm = -3e38f;
      #pragma unroll
      for (int k = 0; k < 9; ++k) mm = fmaxf(mm, av[k]);
      float ss = 0.f;
      #pragma unroll
      for (int k = 0; k < 9; ++k) ss += __expf(av[k] - mm);
      alpha = mm + __logf(ss);
    }
    float v = alpha + cend[jj];
    float av[9];
    #pragma unroll
    for (int k = 0; k < 9; ++k) av[k] = __shfl(v, gbase + k);
    float mm = -3e38f;
    #pragma unroll
    for (int k = 0; k < 9; ++k) mm = fmaxf(mm, av[k]);
    float ss = 0.f;
    #pragma unroll
    for (int k = 0; k < 9; ++k) ss += __expf(av[k] - mm);
    if (act && j == 0) denb[b] = mm + __logf(ss);
  }
  __syncthreads();
  if (tid == 0){
    float s = 0.f;
    #pragma unroll
    for (int b = 0; b < 8; ++b) s += numb[b] - denb[b];
    out[0] = -(s * 0.125f);
  }
}

// ---------- host ----------
extern "C" void kernel_launch(void* const* d_in, const int* in_sizes, int n_in,
                              void* d_out, int out_size, void* d_ws, size_t ws_size,
                              hipStream_t stream){
  const int*   input_ids = (const int*)d_in[0];
  const int*   amask     = (const int*)d_in[1];
  const int*   ttids     = (const int*)d_in[2];
  const int*   labels    = (const int*)d_in[3];
  const float* word_emb  = (const float*)d_in[4];
  const float* pos_emb   = (const float*)d_in[5];
  const float* type_emb  = (const float*)d_in[6];
  const float* eln_s     = (const float*)d_in[7];
  const float* eln_b     = (const float*)d_in[8];
  const float* Wqkv      = (const float*)d_in[9];
  const float* bqkv      = (const float*)d_in[10];
  const float* Wo        = (const float*)d_in[11];
  const float* bo        = (const float*)d_in[12];
  const float* ln1s      = (const float*)d_in[13];
  const float* ln1b      = (const float*)d_in[14];
  const float* W1        = (const float*)d_in[15];
  const float* b1        = (const float*)d_in[16];
  const float* W2        = (const float*)d_in[17];
  const float* b2        = (const float*)d_in[18];
  const float* ln2s      = (const float*)d_in[19];
  const float* ln2b      = (const float*)d_in[20];
  const float* Wt        = (const float*)d_in[21];
  const float* bt        = (const float*)d_in[22];
  const float* cstart    = (const float*)d_in[23];
  const float* cend      = (const float*)d_in[24];
  const float* ctrans    = (const float*)d_in[25];

  char* w = (char*)d_ws;
  auto alloc = [&](size_t sz){ char* p = w; w += (sz + 255) & ~(size_t)255; return p; };
  u16*   xb     = (u16*)  alloc(4096ULL * 768 * 2);
  u8*    xb8    = (u8*)   alloc(4096ULL * 768);
  u16*   qkvb   = (u16*)  alloc(4096ULL * 2304 * 2);
  u16*   ctxb   = (u16*)  alloc(4096ULL * 768 * 2);
  u8*    hb8    = (u8*)   alloc(4096ULL * 3072);
  u16*   Vtb    = (u16*)  alloc(96ULL * 64 * 512 * 2);
  u16*   pbuf   = (u16*)  alloc(4ULL * 4096 * 768 * 2);
  u16*   Wqkv_b = (u16*)  alloc(12ULL * 2304 * 768 * 2);
  u16*   Wo_b   = (u16*)  alloc(12ULL * 768 * 768 * 2);
  u8*    W1_8   = (u8*)   alloc(12ULL * 3072 * 768);
  u8*    W2_8   = (u8*)   alloc(12ULL * 768 * 3072);
  float* emis   = (float*)alloc(8ULL * 512 * 9 * 4);
  float* chunkP = (float*)alloc(8ULL * 16 * 81 * 4);
  (void)ws_size; (void)in_sizes; (void)n_in; (void)out_size;

  embed_ln<<<1024, 256, 0, stream>>>(input_ids, ttids, word_emb, pos_emb, type_emb,
                                     eln_s, eln_b, xb);
  transcvt_l<<<dim3(72, 24, 12), 256, 0, stream>>>(Wqkv, Wqkv_b, 768, 2304);
  transcvt_l<<<dim3(24, 24, 12), 256, 0, stream>>>(Wo, Wo_b, 768, 768);
  transcvt8_l<<<dim3(96, 24, 12), 256, 0, stream>>>(W1, W1_8, 768, 3072);
  transcvt8_l<<<dim3(24, 96, 12), 256, 0, stream>>>(W2, W2_8, 3072, 768);

  for (int l = 0; l < 12; ++l){
    gemm_bt<3, 2><<<dim3(18, 32), 256, 0, stream>>>(xb, Wqkv_b + (size_t)l * 2304 * 768,
        bqkv + (size_t)l * 2304, qkvb, Vtb, 4096, 2304, 768);
    attn_fused<<<dim3(8, 12, 8), 256, 0, stream>>>(qkvb, amask, Vtb, ctxb);
    gemm_bt_sk<2><<<dim3(6, 32, 2), 256, 0, stream>>>(ctxb, Wo_b + (size_t)l * 768 * 768,
        pbuf, 4096, 768, 768);
    res_ln_p<2, 1><<<1024, 256, 0, stream>>>(pbuf, xb, bo + (size_t)l * 768,
        ln1s + (size_t)l * 768, ln1b + (size_t)l * 768, xb, xb8);
    gemm8<1, 2, 1><<<dim3(24, 32), 256, 0, stream>>>(xb8, W1_8 + (size_t)l * 3072 * 768,
        b1 + (size_t)l * 3072, hb8, 4096, 3072, 768);
    gemm8<2, 1, 4><<<dim3(6, 32, 4), 256, 0, stream>>>(hb8, W2_8 + (size_t)l * 768 * 3072,
        nullptr, pbuf, 4096, 768, 3072);
    res_ln_p<4, 0><<<1024, 256, 0, stream>>>(pbuf, xb, b2 + (size_t)l * 768,
        ln2s + (size_t)l * 768, ln2b + (size_t)l * 768, xb, nullptr);
  }
  emis_k<<<1024, 256, 0, stream>>>(xb, Wt, bt, emis);
  crf_chunk<<<128, 128, 0, stream>>>(emis, amask, ctrans, chunkP);
  crf_final<<<1, 128, 0, stream>>>(emis, labels, amask, cstart, cend, ctrans, chunkP,
                                   (float*)d_out);
}